// Round 2
// baseline (941.743 us; speedup 1.0000x reference)
//
#include <hip/hip_runtime.h>
#include <math.h>

#define NQ      6400
#define NCAMS   6
#define LTOT    7979
#define DM      256
#define DFFN    1024

typedef __attribute__((ext_vector_type(8))) short bf16x8;
typedef __attribute__((ext_vector_type(4))) float f32x4;
typedef __attribute__((ext_vector_type(2))) float f32x2;

__device__ inline unsigned short f32_to_bf16(float f) {
    unsigned u = __float_as_uint(f);
    unsigned r = u + 0x7FFF + ((u >> 16) & 1);   // round-to-nearest-even
    return (unsigned short)(r >> 16);
}

// ---------------------------------------------------------------------------
// wt_head: transpose+convert only the weights the head kernel needs.
// wsT layout (shorts): WvT@0, WqT@65536 ([384][256]). 160 blocks.
// ---------------------------------------------------------------------------
__global__ __launch_bounds__(256) void wt_head_kernel(
    const float* __restrict__ Wv, const float* __restrict__ Woff,
    const float* __restrict__ Wattn, unsigned short* __restrict__ wsT)
{
    int b = blockIdx.x;
    const float* src; int K, N, t0, dstoff;
    if (b < 64)       { src = Wv;    K = 256; N = 256; t0 = 0;   dstoff = 0; }
    else if (b < 128) { src = Woff;  K = 256; N = 256; t0 = 64;  dstoff = 65536; }
    else              { src = Wattn; K = 256; N = 128; t0 = 128; dstoff = 131072; }
    int t = b - t0;
    int ntn = N >> 5;
    int kt = t / ntn, nt = t - kt * ntn;
    __shared__ float tile[32][33];
    int tx = threadIdx.x & 31, ty = threadIdx.x >> 5;
    #pragma unroll
    for (int i = 0; i < 4; ++i)
        tile[ty + i * 8][tx] = src[(size_t)(kt * 32 + ty + i * 8) * N + nt * 32 + tx];
    __syncthreads();
    #pragma unroll
    for (int i = 0; i < 4; ++i) {
        int nn = nt * 32 + ty + i * 8;
        wsT[dstoff + (size_t)nn * K + kt * 32 + tx] = f32_to_bf16(tile[tx][ty + i * 8]);
    }
}

// ---------------------------------------------------------------------------
// head_kernel: merged value projection + query projections.
//  b <  750 : value proj (BM=BN=128) -> vb FP8 e4m3 head-major
//             (cam, head, pixel, 32ch PERMUTED c' = 2*(c&15)+(c>>4)), 32 B rows.
//             Channel interleave lets each lane pack 2 fp8 per ushort store.
//  else     : query projections (BM=64): bx=0,1 -> qoff (bf16);
//             bx=2 -> softmax -> qaw (bf16)
// ---------------------------------------------------------------------------
__global__ __launch_bounds__(256) void head_kernel(
    const float* __restrict__ value, const float* __restrict__ query,
    const unsigned short* __restrict__ WvT, const unsigned short* __restrict__ WqT,
    const float* __restrict__ bv, const float* __restrict__ boff,
    const float* __restrict__ battn,
    unsigned char* __restrict__ vb, unsigned short* __restrict__ qoffb,
    unsigned short* __restrict__ qawb)
{
    __shared__ __align__(16) unsigned char smem[20480];
    const int b = blockIdx.x;
    const int tid = threadIdx.x;
    const int wave = tid >> 6, lane = tid & 63;
    const int wm = wave >> 1, wn = wave & 1;
    const int quad = lane >> 4, l16 = lane & 15;

    if (b < 750) {
        unsigned short (*As)[40] = (unsigned short(*)[40])smem;
        unsigned short (*Bs)[40] = (unsigned short(*)[40])(smem + 10240);
        const int m0 = (b >> 1) * 128, n0 = (b & 1) * 128;
        const int M = NCAMS * LTOT;

        f32x4 acc[4][4] = {};

        for (int k0 = 0; k0 < 256; k0 += 32) {
            #pragma unroll
            for (int i = 0; i < 2; ++i) {          // A: 128x32 fp32 -> bf16
                int idx = tid + 256 * i;
                int r = idx >> 2, kc = (idx & 3) * 8;
                int gr = m0 + r;
                float4 f0, f1;
                if (gr < M) {
                    f0 = *(const float4*)(value + (size_t)gr * 256 + k0 + kc);
                    f1 = *(const float4*)(value + (size_t)gr * 256 + k0 + kc + 4);
                } else { f0 = make_float4(0.f,0.f,0.f,0.f); f1 = f0; }
                uint4 o;
                o.x = f32_to_bf16(f0.x) | ((unsigned)f32_to_bf16(f0.y) << 16);
                o.y = f32_to_bf16(f0.z) | ((unsigned)f32_to_bf16(f0.w) << 16);
                o.z = f32_to_bf16(f1.x) | ((unsigned)f32_to_bf16(f1.y) << 16);
                o.w = f32_to_bf16(f1.z) | ((unsigned)f32_to_bf16(f1.w) << 16);
                *(uint4*)&As[r][kc] = o;
            }
            #pragma unroll
            for (int i = 0; i < 2; ++i) {          // B: WvT bf16, uint4
                int idx = tid + 256 * i;
                int r = idx >> 2, kc = (idx & 3) * 8;
                *(uint4*)&Bs[r][kc] = *(const uint4*)(WvT + (size_t)(n0 + r) * 256 + k0 + kc);
            }
            __syncthreads();
            bf16x8 af[4], bfr[4];
            #pragma unroll
            for (int mi = 0; mi < 4; ++mi)
                af[mi] = *(const bf16x8*)&As[wm * 64 + mi * 16 + l16][quad * 8];
            #pragma unroll
            for (int ni = 0; ni < 4; ++ni)
                bfr[ni] = *(const bf16x8*)&Bs[wn * 64 + ni * 16 + l16][quad * 8];
            #pragma unroll
            for (int mi = 0; mi < 4; ++mi)
                #pragma unroll
                for (int ni = 0; ni < 4; ++ni)
                    acc[mi][ni] = __builtin_amdgcn_mfma_f32_16x16x32_bf16(
                        af[mi], bfr[ni], acc[mi][ni], 0, 0, 0);
            __syncthreads();
        }

        // epilogue: pack channel pairs (c, c+16) -> adjacent bytes (2c', 2c'+1)
        #pragma unroll
        for (int mi = 0; mi < 4; ++mi) {
            #pragma unroll
            for (int r = 0; r < 4; ++r) {
                int gm = m0 + wm * 64 + mi * 16 + quad * 4 + r;
                if (gm >= M) continue;
                int cam = gm / LTOT;
                int pix = gm - cam * LTOT;
                #pragma unroll
                for (int p = 0; p < 2; ++p) {
                    int gn0 = n0 + wn * 64 + p * 32 + l16;   // c = l16 (mod 32)
                    int head = gn0 >> 5;
                    float v0 = acc[mi][2 * p][r]     + bv[gn0];
                    float v1 = acc[mi][2 * p + 1][r] + bv[gn0 + 16];
                    int pk = __builtin_amdgcn_cvt_pk_fp8_f32(v0, v1, 0, false);
                    *(unsigned short*)(vb + (((size_t)(cam * 8 + head)) * LTOT + pix) * 32
                                       + 2 * l16) = (unsigned short)pk;
                }
            }
        }
    } else {
        unsigned short (*As)[40] = (unsigned short(*)[40])smem;
        unsigned short (*Bs)[40] = (unsigned short(*)[40])(smem + 5120);
        const int t = b - 750;
        const int bx = t / 100, by = t % 100;
        const int m0 = by * 64, n0 = bx * 128;
        const int is_attn = (bx == 2);

        f32x4 acc[2][4] = {};

        for (int k0 = 0; k0 < 256; k0 += 32) {
            {                                       // A: 64x32 fp32 -> bf16
                int r = tid >> 2, kc = (tid & 3) * 8;
                float4 f0 = *(const float4*)(query + (size_t)(m0 + r) * 256 + k0 + kc);
                float4 f1 = *(const float4*)(query + (size_t)(m0 + r) * 256 + k0 + kc + 4);
                uint4 o;
                o.x = f32_to_bf16(f0.x) | ((unsigned)f32_to_bf16(f0.y) << 16);
                o.y = f32_to_bf16(f0.z) | ((unsigned)f32_to_bf16(f0.w) << 16);
                o.z = f32_to_bf16(f1.x) | ((unsigned)f32_to_bf16(f1.y) << 16);
                o.w = f32_to_bf16(f1.z) | ((unsigned)f32_to_bf16(f1.w) << 16);
                *(uint4*)&As[r][kc] = o;
            }
            #pragma unroll
            for (int i = 0; i < 2; ++i) {           // B: WqT bf16, uint4
                int idx = tid + 256 * i;
                int r = idx >> 2, kc = (idx & 3) * 8;
                *(uint4*)&Bs[r][kc] = *(const uint4*)(WqT + (size_t)(n0 + r) * 256 + k0 + kc);
            }
            __syncthreads();
            bf16x8 af[2], bfr[4];
            #pragma unroll
            for (int mi = 0; mi < 2; ++mi)
                af[mi] = *(const bf16x8*)&As[wm * 32 + mi * 16 + l16][quad * 8];
            #pragma unroll
            for (int ni = 0; ni < 4; ++ni)
                bfr[ni] = *(const bf16x8*)&Bs[wn * 64 + ni * 16 + l16][quad * 8];
            #pragma unroll
            for (int mi = 0; mi < 2; ++mi)
                #pragma unroll
                for (int ni = 0; ni < 4; ++ni)
                    acc[mi][ni] = __builtin_amdgcn_mfma_f32_16x16x32_bf16(
                        af[mi], bfr[ni], acc[mi][ni], 0, 0, 0);
            __syncthreads();
        }

        if (is_attn) {
            #pragma unroll
            for (int mi = 0; mi < 2; ++mi) {
                #pragma unroll
                for (int r = 0; r < 4; ++r) {
                    int gm = m0 + wm * 32 + mi * 16 + quad * 4 + r;
                    #pragma unroll
                    for (int ni = 0; ni < 4; ++ni) {
                        int gn = wn * 64 + ni * 16 + l16;
                        float v = acc[mi][ni][r] + battn[gn];
                        float mx = v;
                        #pragma unroll
                        for (int s = 1; s < 16; s <<= 1)
                            mx = fmaxf(mx, __shfl_xor(mx, s, 64));
                        float e = __expf(v - mx);
                        float sum = e;
                        #pragma unroll
                        for (int s = 1; s < 16; s <<= 1)
                            sum += __shfl_xor(sum, s, 64);
                        qawb[(size_t)gm * 128 + gn] = f32_to_bf16(e / sum);
                    }
                }
            }
        } else {
            #pragma unroll
            for (int mi = 0; mi < 2; ++mi) {
                #pragma unroll
                for (int r = 0; r < 4; ++r) {
                    int gm = m0 + wm * 32 + mi * 16 + quad * 4 + r;
                    #pragma unroll
                    for (int ni = 0; ni < 4; ++ni) {
                        int gn = n0 + wn * 64 + ni * 16 + l16;
                        qoffb[(size_t)gm * 256 + gn] = f32_to_bf16(acc[mi][ni][r] + boff[gn]);
                    }
                }
            }
        }
    }
}

// ---------------------------------------------------------------------------
// sample_kernel: b < 3200 -> head-partitioned fp8 deformable sampling;
// b >= 3200 -> tail weight transpose (Wout/W1/W2 -> WoT/W1T/W2T).
// Cam loop split into 2 phases of 3 cams: s_tab shrinks to 13.1 KB so
// 8 blocks/CU (32 waves, HW max) are resident -> latency hiding for the
// gather phase. Gathers use a wave-uniform slice base + 32-bit per-lane
// offset (cg2*16 folded into the offset) for SGPR-base addressing.
// vb channels are interleave-permuted; outsum is written in permuted order
// and WoT's K index is permuted to match (see tail transpose).
// ---------------------------------------------------------------------------
__global__ __launch_bounds__(256, 8) void sample_kernel(
    const unsigned char* __restrict__ vb,  // (6, 8, 7979, 32) fp8 e4m3, ch-permuted
    const unsigned short* __restrict__ qoffb, // (6400, 256) bf16
    const unsigned short* __restrict__ qawb,  // (6400, 128) bf16
    const float* __restrict__ refpts,      // (6, 1, 6400, 4, 2)
    const int*   __restrict__ bev_mask,    // (6, 1, 6400, 4)
    const float* __restrict__ Wout, const float* __restrict__ W1,
    const float* __restrict__ W2,
    unsigned short* __restrict__ outsum,   // (6400, 256) bf16 (ch-permuted)
    float* __restrict__ visb,              // (6400)
    unsigned short* __restrict__ wsT)
{
    __shared__ __align__(16) unsigned s_tab[3][272][4];   // [cam-in-phase][sq*17+tup][corner]
    __shared__ float s_vis[NCAMS][16];
    __shared__ int   s_nvis[16];

    const int bid = blockIdx.x;
    const int tid = threadIdx.x;

    if (bid >= 3200) {
        // ---- tail weight transpose (reuses s_tab as the LDS tile) ----
        int t = bid - 3200;
        const float* src; int K, N, dstoff;
        if (t < 64)       { src = Wout; K = 256;  N = 256;  dstoff = 163840; }
        else if (t < 320) { src = W1;   K = 256;  N = 1024; dstoff = 229376; t -= 64; }
        else              { src = W2;   K = 1024; N = 256;  dstoff = 491520; t -= 320; }
        int ntn = N >> 5;
        int kt = t / ntn, nt = t - kt * ntn;
        float (*tile)[33] = (float(*)[33])&s_tab[0][0][0];
        int tx = tid & 31, ty = tid >> 5;
        #pragma unroll
        for (int i = 0; i < 4; ++i)
            tile[ty + i * 8][tx] = src[(size_t)(kt * 32 + ty + i * 8) * N + nt * 32 + tx];
        __syncthreads();
        // WoT only: permute K index within each 32-channel head block to match
        // the vb/outsum channel interleave: c' = 2*(c&15) | (c>>4)
        int txp = (dstoff == 163840) ? (((tx & 15) << 1) | (tx >> 4)) : tx;
        #pragma unroll
        for (int i = 0; i < 4; ++i) {
            int nn = nt * 32 + ty + i * 8;
            wsT[dstoff + (size_t)nn * K + kt * 32 + txp] = f32_to_bf16(tile[tx][ty + i * 8]);
        }
        return;
    }

    const int h   = bid & 7;
    const int q0  = (bid >> 3) * 16;
    const int sq  = tid >> 4;
    const int tup = tid & 15;
    const int lvl = tup >> 2;
    const int n_s = q0 + sq;

    if (tid < 96) {
        int cam = tid >> 4, q = tid & 15;
        const int* bm = bev_mask + ((size_t)cam * NQ + q0 + q) * 4;
        s_vis[cam][q] = ((bm[0] + bm[1] + bm[2] + bm[3]) > 0) ? 1.f : 0.f;
    }
    __syncthreads();
    if (tid >= 32 && tid < 48) {
        int q = tid - 32;
        float s = 0.f;
        #pragma unroll
        for (int cam = 0; cam < NCAMS; ++cam) s += s_vis[cam][q];
        s_nvis[q] = (int)s;
    }

    unsigned uoff = *(const unsigned*)(qoffb + (size_t)n_s * 256 + h * 32 + tup * 2);
    const float offx  = __uint_as_float(uoff << 16);
    const float offy  = __uint_as_float(uoff & 0xFFFF0000u);
    const float my_aw = __uint_as_float((unsigned)qawb[(size_t)n_s * 128 + h * 16 + tup] << 16);
    const int Wl   = (lvl == 0) ? 100 : (lvl == 1) ? 50 : (lvl == 2) ? 25 : 13;
    const int Hl   = (lvl == 0) ? 60  : (lvl == 1) ? 30 : (lvl == 2) ? 15 : 8;
    const int base = (lvl == 0) ? 0   : (lvl == 1) ? 6000 : (lvl == 2) ? 7500 : 7875;
    const float dx = offx / (float)Wl;
    const float dy = offy / (float)Hl;
    const int tabi = sq * 17 + tup;

    float2 rp[NCAMS];
    #pragma unroll
    for (int k = 0; k < NCAMS; ++k)
        rp[k] = *(const float2*)(refpts + (((size_t)k * NQ + n_s) * 4 + lvl) * 2);

    const int tp   = (tid >> 1) & 7;
    const int cg2  = tid & 1;
    const int cg16 = cg2 * 16;

    f32x2 A[8] = {};

    #pragma unroll
    for (int ph = 0; ph < 2; ++ph) {
        // ---- build sampling tables for cams [ph*3, ph*3+3) ----
        #pragma unroll
        for (int kk = 0; kk < 3; ++kk) {
            int k = ph * 3 + kk;
            float fx = (rp[k].x + dx) * (float)Wl - 0.5f;
            float fy = (rp[k].y + dy) * (float)Hl - 0.5f;
            float x0f = floorf(fx), y0f = floorf(fy);
            float lx = fx - x0f, ly = fy - y0f;
            int x0 = (int)x0f, y0 = (int)y0f;
            int x1 = x0 + 1, y1 = y0 + 1;
            float wb = my_aw * s_vis[k][sq];
            float w00 = (1.f - lx) * (1.f - ly) * wb;
            float w01 = lx * (1.f - ly) * wb;
            float w10 = (1.f - lx) * ly * wb;
            float w11 = lx * ly * wb;
            bool vx0 = (x0 >= 0) & (x0 < Wl), vx1 = (x1 >= 0) & (x1 < Wl);
            bool vy0 = (y0 >= 0) & (y0 < Hl), vy1 = (y1 >= 0) & (y1 < Hl);
            uint4 o;
            o.x = (vx0 & vy0) ? (((unsigned)(base + y0 * Wl + x0) << 16) | f32_to_bf16(w00)) : 0u;
            o.y = (vx1 & vy0) ? (((unsigned)(base + y0 * Wl + x1) << 16) | f32_to_bf16(w01)) : 0u;
            o.z = (vx0 & vy1) ? (((unsigned)(base + y1 * Wl + x0) << 16) | f32_to_bf16(w10)) : 0u;
            o.w = (vx1 & vy1) ? (((unsigned)(base + y1 * Wl + x1) << 16) | f32_to_bf16(w11)) : 0u;
            *(uint4*)&s_tab[kk][tabi][0] = o;
        }
        __syncthreads();

        // ---- accumulate cams [ph*3, ph*3+3) ----
        #pragma unroll
        for (int kk = 0; kk < 3; ++kk) {
            int k = ph * 3 + kk;
            const unsigned char* vkh =            // wave-uniform slice base
                vb + (size_t)((k * 8 + h) * (LTOT * 32));
            #pragma unroll
            for (int t = 0; t < 2; ++t) {
                uint4 t4 = *(const uint4*)&s_tab[kk][sq * 17 + tp * 2 + t][0];
                #pragma unroll
                for (int corner = 0; corner < 4; ++corner) {
                    unsigned tc = (corner == 0) ? t4.x : (corner == 1) ? t4.y
                                : (corner == 2) ? t4.z : t4.w;
                    float w = __uint_as_float(tc << 16);
                    f32x2 w2 = {w, w};
                    int off = (int)((tc >> 16) << 5) + cg16;   // 32-bit lane offset
                    uint4 d = *(const uint4*)(vkh + off);
                    A[0] += w2 * __builtin_amdgcn_cvt_pk_f32_fp8(d.x, false);
                    A[1] += w2 * __builtin_amdgcn_cvt_pk_f32_fp8(d.x, true);
                    A[2] += w2 * __builtin_amdgcn_cvt_pk_f32_fp8(d.y, false);
                    A[3] += w2 * __builtin_amdgcn_cvt_pk_f32_fp8(d.y, true);
                    A[4] += w2 * __builtin_amdgcn_cvt_pk_f32_fp8(d.z, false);
                    A[5] += w2 * __builtin_amdgcn_cvt_pk_f32_fp8(d.z, true);
                    A[6] += w2 * __builtin_amdgcn_cvt_pk_f32_fp8(d.w, false);
                    A[7] += w2 * __builtin_amdgcn_cvt_pk_f32_fp8(d.w, true);
                }
            }
        }
        __syncthreads();   // table buffer reused by next phase
    }

    // reduce across the 8 tap-threads (lane bits 1..3)
    #pragma unroll
    for (int i = 0; i < 8; ++i) {
        float x0 = A[i].x, x1 = A[i].y;
        x0 += __shfl_xor(x0, 2, 64); x1 += __shfl_xor(x1, 2, 64);
        x0 += __shfl_xor(x0, 4, 64); x1 += __shfl_xor(x1, 4, 64);
        x0 += __shfl_xor(x0, 8, 64); x1 += __shfl_xor(x1, 8, 64);
        A[i].x = x0; A[i].y = x1;
    }

    if ((tid & 14) == 0) {          // tp == 0: two writers per query (cg2 = 0,1)
        int nv = s_nvis[sq];
        float sc = 1.f / (float)(nv > 0 ? nv : 1);
        uint4 o0, o1;
        o0.x = f32_to_bf16(A[0].x * sc) | ((unsigned)f32_to_bf16(A[0].y * sc) << 16);
        o0.y = f32_to_bf16(A[1].x * sc) | ((unsigned)f32_to_bf16(A[1].y * sc) << 16);
        o0.z = f32_to_bf16(A[2].x * sc) | ((unsigned)f32_to_bf16(A[2].y * sc) << 16);
        o0.w = f32_to_bf16(A[3].x * sc) | ((unsigned)f32_to_bf16(A[3].y * sc) << 16);
        o1.x = f32_to_bf16(A[4].x * sc) | ((unsigned)f32_to_bf16(A[4].y * sc) << 16);
        o1.y = f32_to_bf16(A[5].x * sc) | ((unsigned)f32_to_bf16(A[5].y * sc) << 16);
        o1.z = f32_to_bf16(A[6].x * sc) | ((unsigned)f32_to_bf16(A[6].y * sc) << 16);
        o1.w = f32_to_bf16(A[7].x * sc) | ((unsigned)f32_to_bf16(A[7].y * sc) << 16);
        *(uint4*)(outsum + (size_t)n_s * 256 + h * 32 + cg2 * 16)     = o0;
        *(uint4*)(outsum + (size_t)n_s * 256 + h * 32 + cg2 * 16 + 8) = o1;
    }
    if (h == 0 && tid < 16) visb[q0 + tid] = (s_nvis[tid] > 0) ? 1.f : 0.f;
}

// ---------------------------------------------------------------------------
// Fused output-projection + residual + LN1 (phase-1 only of the old fused
// kernel; FFN1 moved to a wide gemm64 launch for occupancy).
// BM=32 BN=256 K=256: x = LN(outsum@WoT + residual algebra), written to
// xout (fp32, for LN2) and xb16 (bf16, A-operand of FFN1).
// ---------------------------------------------------------------------------
__global__ __launch_bounds__(256) void projln1_kernel(
    const unsigned short* __restrict__ A, const unsigned short* __restrict__ BT,
    const float* __restrict__ query, const float* __restrict__ visb,
    const float* __restrict__ b_out, const float* __restrict__ g,
    const float* __restrict__ b,
    float* __restrict__ xout, unsigned short* __restrict__ xb16)
{
    const int K = 256;
    __shared__ __align__(16) unsigned short As[32][40];
    __shared__ __align__(16) unsigned short Bs[256][40];
    __shared__ float sred[2][4][4][2];
    __shared__ float ssred[2][4][4][2];
    __shared__ float s_mu[32], s_rs[32];

    const int tid  = threadIdx.x;
    const int wave = tid >> 6, lane = tid & 63;
    const int wm = wave >> 1, wn = wave & 1;
    const int quad = lane >> 4, l16 = lane & 15;
    const int m0 = blockIdx.x * 32;

    f32x4 acc[8] = {};

    for (int k0 = 0; k0 < K; k0 += 32) {
        {
            int r = tid >> 3, kc = (tid & 7) * 4;
            *(uint2*)&As[r][kc] = *(const uint2*)(A + (size_t)(m0 + r) * K + k0 + kc);
        }
        {
            const unsigned short* src = BT + (size_t)tid * K + k0;
            *(uint4*)&Bs[tid][0]  = *(const uint4*)(src);
            *(uint4*)&Bs[tid][8]  = *(const uint4*)(src + 8);
            *(uint4*)&Bs[tid][16] = *(const uint4*)(src + 16);
            *(uint4*)&Bs[tid][24] = *(const uint4*)(src + 24);
        }
        __syncthreads();
        bf16x8 af = *(const bf16x8*)&As[wm * 16 + l16][quad * 8];
        #pragma unroll
        for (int ni = 0; ni < 8; ++ni) {
            bf16x8 bfr = *(const bf16x8*)&Bs[wn * 128 + ni * 16 + l16][quad * 8];
            acc[ni] = __builtin_amdgcn_mfma_f32_16x16x32_bf16(af, bfr, acc[ni], 0, 0, 0);
        }
        __syncthreads();
    }

    float vals[8][4];
    #pragma unroll
    for (int r = 0; r < 4; ++r) {
        int gm = m0 + wm * 16 + quad * 4 + r;
        float vs = visb[gm];
        float s = 0.f, ss = 0.f;
        #pragma unroll
        for (int ni = 0; ni < 8; ++ni) {
            int gn = wn * 128 + ni * 16 + l16;
            float v = acc[ni][r] + vs * b_out[gn]
                    + query[(size_t)gm * 256 + gn] * (1.f + vs);
            vals[ni][r] = v;
            s += v; ss += v * v;
        }
        #pragma unroll
        for (int m = 1; m < 16; m <<= 1) {
            s  += __shfl_xor(s,  m, 64);
            ss += __shfl_xor(ss, m, 64);
        }
        if (l16 == 0) {
            sred[wm][quad][r][wn]  = s;
            ssred[wm][quad][r][wn] = ss;
        }
    }
    __syncthreads();
    if (tid < 32) {
        int lwm = tid >> 4, lq = (tid >> 2) & 3, lr = tid & 3;
        float s  = sred[lwm][lq][lr][0]  + sred[lwm][lq][lr][1];
        float ss = ssred[lwm][lq][lr][0] + ssred[lwm][lq][lr][1];
        float mu = s * (1.f / 256.f);
        float var = ss * (1.f / 256.f) - mu * mu;
        s_mu[tid] = mu;
        s_rs[tid] = rsqrtf(var + 1e-5f);
    }
    __syncthreads();

    #pragma unroll
    for (int r = 0; r < 4; ++r) {
        int rowl = wm * 16 + quad * 4 + r;
        int gm = m0 + rowl;
        float mu = s_mu[rowl], rs = s_rs[rowl];
        #pragma unroll
        for (int ni = 0; ni < 8; ++ni) {
            int gn = wn * 128 + ni * 16 + l16;
            float res = (vals[ni][r] - mu) * rs * g[gn] + b[gn];
            xout[(size_t)gm * 256 + gn] = res;
            xb16[(size_t)gm * 256 + gn] = f32_to_bf16(res);
        }
    }
}

// ---------------------------------------------------------------------------
// MFMA bf16 GEMM, BM=64 BN=128 BK=32, bf16 A + BT. Split-K over gridDim.z.
// mode 1: relu -> bf16 out; mode 2: plain bf16 out (split-K partials).
// ---------------------------------------------------------------------------
__global__ __launch_bounds__(256) void gemm64_kernel(
    const unsigned short* __restrict__ A, const unsigned short* __restrict__ BT,
    const float* __restrict__ bias, unsigned short* __restrict__ Cb,
    int M, int N, int K, int mode)
{
    __shared__ __align__(16) unsigned short As[64][40];
    __shared__ __align__(16) unsigned short Bs[128][40];

    const int tid  = threadIdx.x;
    const int wave = tid >> 6, lane = tid & 63;
    const int wm = wave >> 1, wn = wave & 1;
    const int quad = lane >> 4, l16 = lane & 15;
    const int m0 = blockIdx.y * 64, n0 = blockIdx.x * 128;
    const int nz = gridDim.z;
    const int klen = K / nz;
    const int kbase = blockIdx.z * klen;

    f32x4 acc[2][4] = {};

    for (int k0 = kbase; k0 < kbase + klen; k0 += 32) {
        {
            int r = tid >> 2, kc = (tid & 3) * 8;
            int gr = m0 + r;
            uint4 d = (gr < M) ? *(const uint4*)(A + (size_t)gr * K + k0 + kc)
                               : make_uint4(0u, 0u, 0u, 0u);
            *(uint4*)&As[r][kc] = d;
        }
        #pragma unroll
        for (int i = 0; i < 2; ++i) {
            int idx = tid + 256 * i;
            int r = idx >> 2, kc = (idx & 3) * 8;
            *(uint4*)&Bs[r][kc] = *(const uint4*)(BT + (size_t)(n0 + r) * K + k0 + kc);
        }
        __syncthreads();
        bf16x8 af[2], bfr[4];
        #pragma unroll
        for (int mi = 0; mi < 2; ++mi)
            af[mi] = *(const bf16x8*)&As[wm * 32 + mi * 16 + l16][quad * 8];
        #pragma unroll
        for (int ni = 0; ni < 4; ++ni)
            bfr[ni] = *(const bf16x8*)&Bs[wn * 64 + ni * 16 + l16][quad * 8];
        #pragma unroll
        for (int mi = 0; mi < 2; ++mi)
            #pragma unroll
            for (int ni = 0; ni < 4; ++ni)
                acc[mi][ni] = __builtin_amdgcn_mfma_f32_16x16x32_bf16(
                    af[mi], bfr[ni], acc[mi][ni], 0, 0, 0);
        __syncthreads();
    }

    const float* bz = (blockIdx.z == 0) ? bias : nullptr;
    unsigned short* Cz = Cb + (size_t)blockIdx.z * M * N;

    #pragma unroll
    for (int mi = 0; mi < 2; ++mi) {
        #pragma unroll
        for (int r = 0; r < 4; ++r) {
            int gm = m0 + wm * 32 + mi * 16 + quad * 4 + r;
            if (gm >= M) continue;
            #pragma unroll
            for (int ni = 0; ni < 4; ++ni) {
                int gn = n0 + wn * 64 + ni * 16 + l16;
                float v = acc[mi][ni][r] + (bz ? bz[gn] : 0.f);
                if (mode == 1) v = fmaxf(v, 0.f);
                Cz[(size_t)gm * N + gn] = f32_to_bf16(v);
            }
        }
    }
}

// ---------------------------------------------------------------------------
// Vectorized LN2: one wave per row; x fp32 + two bf16 split-K halves.
// ---------------------------------------------------------------------------
__global__ __launch_bounds__(256) void ln2v_kernel(
    const float* __restrict__ x, const unsigned short* __restrict__ f0,
    const unsigned short* __restrict__ f1,
    const float* __restrict__ g, const float* __restrict__ b,
    float* __restrict__ out)
{
    int row  = blockIdx.x * 4 + (threadIdx.x >> 6);
    int lane = threadIdx.x & 63;
    size_t base = (size_t)row * 256 + lane * 4;
    float4 xv = *(const float4*)(x + base);
    uint2 u0 = *(const uint2*)(f0 + base);
    uint2 u1 = *(const uint2*)(f1 + base);
    float t0 = xv.x + __uint_as_float(u0.x << 16)        + __uint_as_float(u1.x << 16);
    float t1 = xv.y + __uint_as_float(u0.x & 0xFFFF0000u) + __uint_as_float(u1.x & 0xFFFF0000u);
    float t2 = xv.z + __uint_as_float(u0.y << 16)        + __uint_as_float(u1.y << 16);
    float t3 = xv.w + __uint_as_float(u0.y & 0xFFFF0000u) + __uint_as_float(u1.y & 0xFFFF0000u);
    float s  = t0 + t1 + t2 + t3;
    float ss = t0 * t0 + t1 * t1 + t2 * t2 + t3 * t3;
    #pragma unroll
    for (int m = 1; m < 64; m <<= 1) {
        s  += __shfl_xor(s,  m, 64);
        ss += __shfl_xor(ss, m, 64);
    }
    float mu = s * (1.f / 256.f);
    float rs = rsqrtf(ss * (1.f / 256.f) - mu * mu + 1e-5f);
    float4 gv = *(const float4*)(g + lane * 4);
    float4 bv = *(const float4*)(b + lane * 4);
    float4 o;
    o.x = (t0 - mu) * rs * gv.x + bv.x;
    o.y = (t1 - mu) * rs * gv.y + bv.y;
    o.z = (t2 - mu) * rs * gv.z + bv.z;
    o.w = (t3 - mu) * rs * gv.w + bv.w;
    *(float4*)(out + base) = o;
}

// ---------------------------------------------------------------------------
extern "C" void kernel_launch(void* const* d_in, const int* in_sizes, int n_in,
                              void* d_out, int out_size, void* d_ws, size_t ws_size,
                              hipStream_t stream)
{
    const float* query   = (const float*)d_in[0];
    const float* value   = (const float*)d_in[2];
    const float* refpts  = (const float*)d_in[3];
    const int*   bevmask = (const int*)d_in[6];
    const float* W_value = (const float*)d_in[7];
    const float* b_value = (const float*)d_in[8];
    const float* W_off   = (const float*)d_in[9];
    const float* b_off   = (const float*)d_in[10];
    const float* W_attn  = (const float*)d_in[11];
    const float* b_attn  = (const float*)d_in[12];
    const float* W_out   = (const float*)d_in[13];
    const float* b_out   = (const float*)d_in[14];
    const float* ln1_g   = (const float*)d_in[15];
    const float* ln1_b   = (const float*)d_in[16];
    const float* W1      = (const float*)d_in[17];
    const float* b1      = (const float*)d_in[18];
    const float* W2      = (const float*)d_in[19];
    const float* b2      = (const float*)d_in[20];
    const float* ln2_g   = (const float*)d_in[21];
    const float* ln2_b   = (const float*)d_in[22];
    float* out = (float*)d_out;

    // workspace layout (byte offsets, temporal aliasing):
    //  [0)          vb fp8 12,255,744       (head -> sample)
    //  [0)          xbuf fp32 6,553,600     (projln1 -> ln2) [vb dead]
    //  [13,000,000) hbf bf16 13,107,200     (ffn1 -> ffn2)
    //  [27,000,000) qoffb bf16 3,276,800    (head -> sample)
    //  [27,000,000) xb16 bf16 3,276,800     (projln1 -> ffn1) [qoffb dead]
    //  [31,000,000) qawb bf16 1,638,400     (head -> sample)
    //  [33,000,000) outsum bf16 3,276,800   (sample -> projln1)
    //  [36,500,000) visb 25,600             (sample -> projln1)
    //  [36,600,000) wsT bf16 1,507,328      (wt_head/sample-tail -> GEMMs)
    //  [39,000,000) ffnout bf16 2x3,276,800 (ffn2 -> ln2)
    char* ws = (char*)d_ws;
    unsigned char*  vb     = (unsigned char*)(ws + 0);
    float*          xbuf   = (float*)(ws + 0);
    unsigned short* hbf    = (unsigned short*)(ws + 13000000);
    unsigned short* qoffb  = (unsigned short*)(ws + 27000000);
    unsigned short* xb16   = (unsigned short*)(ws + 27000000);
    unsigned short* qawb   = (unsigned short*)(ws + 31000000);
    unsigned short* outsum = (unsigned short*)(ws + 33000000);
    float*          visb   = (float*)(ws + 36500000);
    unsigned short* wsT    = (unsigned short*)(ws + 36600000);
    unsigned short* ffnout = (unsigned short*)(ws + 39000000);

    unsigned short* WvT = wsT;            // [256][256]
    unsigned short* WqT = wsT + 65536;    // [384][256]
    unsigned short* WoT = wsT + 163840;   // [256][256] (K-permuted)
    unsigned short* W1T = wsT + 229376;   // [1024][256]
    unsigned short* W2T = wsT + 491520;   // [256][1024]

    // L0: head-side weights -> transposed bf16 (160 blocks)
    wt_head_kernel<<<dim3(160), 256, 0, stream>>>(
        W_value, W_off, W_attn, wsT);
    // L1: value proj (750 blocks, fp8 out, ch-permuted) + query proj (300 blocks)
    head_kernel<<<dim3(1050), 256, 0, stream>>>(
        value, query, WvT, WqT, b_value, b_off, b_attn, vb, qoffb, qawb);
    // L2: sampling (3200) + tail weight transpose (576, overlapped)
    sample_kernel<<<dim3(3776), 256, 0, stream>>>(
        vb, qoffb, qawb, refpts, bevmask, W_out, W1, W2, outsum, visb, wsT);
    // L3: x = LN(outsum@WoT + residual) -> xbuf fp32 + xb16 bf16
    projln1_kernel<<<dim3(200), 256, 0, stream>>>(
        outsum, WoT, query, visb, b_out, ln1_g, ln1_b, xbuf, xb16);
    // L4: h = relu(xb16 @ W1 + b1), 800 blocks
    gemm64_kernel<<<dim3(8, 100, 1), 256, 0, stream>>>(
        xb16, W1T, b1, hbf, NQ, DFFN, 256, 1);
    // L5: ffnout[z] = bf16(h @ W2 (+b2 on z=0)), split-K x2
    gemm64_kernel<<<dim3(2, 100, 2), 256, 0, stream>>>(
        hbf, W2T, b2, ffnout, NQ, 256, DFFN, 2);
    // L6: out = LN(x + f0 + f1)
    ln2v_kernel<<<dim3(1600), 256, 0, stream>>>(
        xbuf, ffnout, ffnout + (size_t)NQ * 256, ln2_g, ln2_b, out);
}

// Round 3
// 347.130 us; speedup vs baseline: 2.7129x; 2.7129x over previous
//
#include <hip/hip_runtime.h>
#include <math.h>

#define NQ      6400
#define NCAMS   6
#define LTOT    7979
#define DM      256
#define DFFN    1024

typedef __attribute__((ext_vector_type(8))) short bf16x8;
typedef __attribute__((ext_vector_type(4))) float f32x4;
typedef __attribute__((ext_vector_type(2))) float f32x2;

__device__ inline unsigned short f32_to_bf16(float f) {
    unsigned u = __float_as_uint(f);
    unsigned r = u + 0x7FFF + ((u >> 16) & 1);   // round-to-nearest-even
    return (unsigned short)(r >> 16);
}

// ---------------------------------------------------------------------------
// wt_head: transpose+convert only the weights the head kernel needs.
// wsT layout (shorts): WvT@0, WqT@65536 ([384][256]). 160 blocks.
// ---------------------------------------------------------------------------
__global__ __launch_bounds__(256) void wt_head_kernel(
    const float* __restrict__ Wv, const float* __restrict__ Woff,
    const float* __restrict__ Wattn, unsigned short* __restrict__ wsT)
{
    int b = blockIdx.x;
    const float* src; int K, N, t0, dstoff;
    if (b < 64)       { src = Wv;    K = 256; N = 256; t0 = 0;   dstoff = 0; }
    else if (b < 128) { src = Woff;  K = 256; N = 256; t0 = 64;  dstoff = 65536; }
    else              { src = Wattn; K = 256; N = 128; t0 = 128; dstoff = 131072; }
    int t = b - t0;
    int ntn = N >> 5;
    int kt = t / ntn, nt = t - kt * ntn;
    __shared__ float tile[32][33];
    int tx = threadIdx.x & 31, ty = threadIdx.x >> 5;
    #pragma unroll
    for (int i = 0; i < 4; ++i)
        tile[ty + i * 8][tx] = src[(size_t)(kt * 32 + ty + i * 8) * N + nt * 32 + tx];
    __syncthreads();
    #pragma unroll
    for (int i = 0; i < 4; ++i) {
        int nn = nt * 32 + ty + i * 8;
        wsT[dstoff + (size_t)nn * K + kt * 32 + tx] = f32_to_bf16(tile[tx][ty + i * 8]);
    }
}

// ---------------------------------------------------------------------------
// head_kernel: merged value projection + query projections.
//  b <  750 : value proj (BM=BN=128) -> vb FP8 e4m3 head-major
//             (cam, head, pixel, 32ch PERMUTED c' = 2*(c&15)+(c>>4)), 32 B rows.
//             Channel interleave lets each lane pack 2 fp8 per ushort store.
//  else     : query projections (BM=64): bx=0,1 -> qoff (bf16);
//             bx=2 -> softmax -> qaw (bf16)
// ---------------------------------------------------------------------------
__global__ __launch_bounds__(256) void head_kernel(
    const float* __restrict__ value, const float* __restrict__ query,
    const unsigned short* __restrict__ WvT, const unsigned short* __restrict__ WqT,
    const float* __restrict__ bv, const float* __restrict__ boff,
    const float* __restrict__ battn,
    unsigned char* __restrict__ vb, unsigned short* __restrict__ qoffb,
    unsigned short* __restrict__ qawb)
{
    __shared__ __align__(16) unsigned char smem[20480];
    const int b = blockIdx.x;
    const int tid = threadIdx.x;
    const int wave = tid >> 6, lane = tid & 63;
    const int wm = wave >> 1, wn = wave & 1;
    const int quad = lane >> 4, l16 = lane & 15;

    if (b < 750) {
        unsigned short (*As)[40] = (unsigned short(*)[40])smem;
        unsigned short (*Bs)[40] = (unsigned short(*)[40])(smem + 10240);
        const int m0 = (b >> 1) * 128, n0 = (b & 1) * 128;
        const int M = NCAMS * LTOT;

        f32x4 acc[4][4] = {};

        for (int k0 = 0; k0 < 256; k0 += 32) {
            #pragma unroll
            for (int i = 0; i < 2; ++i) {          // A: 128x32 fp32 -> bf16
                int idx = tid + 256 * i;
                int r = idx >> 2, kc = (idx & 3) * 8;
                int gr = m0 + r;
                float4 f0, f1;
                if (gr < M) {
                    f0 = *(const float4*)(value + (size_t)gr * 256 + k0 + kc);
                    f1 = *(const float4*)(value + (size_t)gr * 256 + k0 + kc + 4);
                } else { f0 = make_float4(0.f,0.f,0.f,0.f); f1 = f0; }
                uint4 o;
                o.x = f32_to_bf16(f0.x) | ((unsigned)f32_to_bf16(f0.y) << 16);
                o.y = f32_to_bf16(f0.z) | ((unsigned)f32_to_bf16(f0.w) << 16);
                o.z = f32_to_bf16(f1.x) | ((unsigned)f32_to_bf16(f1.y) << 16);
                o.w = f32_to_bf16(f1.z) | ((unsigned)f32_to_bf16(f1.w) << 16);
                *(uint4*)&As[r][kc] = o;
            }
            #pragma unroll
            for (int i = 0; i < 2; ++i) {          // B: WvT bf16, uint4
                int idx = tid + 256 * i;
                int r = idx >> 2, kc = (idx & 3) * 8;
                *(uint4*)&Bs[r][kc] = *(const uint4*)(WvT + (size_t)(n0 + r) * 256 + k0 + kc);
            }
            __syncthreads();
            bf16x8 af[4], bfr[4];
            #pragma unroll
            for (int mi = 0; mi < 4; ++mi)
                af[mi] = *(const bf16x8*)&As[wm * 64 + mi * 16 + l16][quad * 8];
            #pragma unroll
            for (int ni = 0; ni < 4; ++ni)
                bfr[ni] = *(const bf16x8*)&Bs[wn * 64 + ni * 16 + l16][quad * 8];
            #pragma unroll
            for (int mi = 0; mi < 4; ++mi)
                #pragma unroll
                for (int ni = 0; ni < 4; ++ni)
                    acc[mi][ni] = __builtin_amdgcn_mfma_f32_16x16x32_bf16(
                        af[mi], bfr[ni], acc[mi][ni], 0, 0, 0);
            __syncthreads();
        }

        // epilogue: pack channel pairs (c, c+16) -> adjacent bytes (2c', 2c'+1)
        #pragma unroll
        for (int mi = 0; mi < 4; ++mi) {
            #pragma unroll
            for (int r = 0; r < 4; ++r) {
                int gm = m0 + wm * 64 + mi * 16 + quad * 4 + r;
                if (gm >= M) continue;
                int cam = gm / LTOT;
                int pix = gm - cam * LTOT;
                #pragma unroll
                for (int p = 0; p < 2; ++p) {
                    int gn0 = n0 + wn * 64 + p * 32 + l16;   // c = l16 (mod 32)
                    int head = gn0 >> 5;
                    float v0 = acc[mi][2 * p][r]     + bv[gn0];
                    float v1 = acc[mi][2 * p + 1][r] + bv[gn0 + 16];
                    int pk = __builtin_amdgcn_cvt_pk_fp8_f32(v0, v1, 0, false);
                    *(unsigned short*)(vb + (((size_t)(cam * 8 + head)) * LTOT + pix) * 32
                                       + 2 * l16) = (unsigned short)pk;
                }
            }
        }
    } else {
        unsigned short (*As)[40] = (unsigned short(*)[40])smem;
        unsigned short (*Bs)[40] = (unsigned short(*)[40])(smem + 5120);
        const int t = b - 750;
        const int bx = t / 100, by = t % 100;
        const int m0 = by * 64, n0 = bx * 128;
        const int is_attn = (bx == 2);

        f32x4 acc[2][4] = {};

        for (int k0 = 0; k0 < 256; k0 += 32) {
            {                                       // A: 64x32 fp32 -> bf16
                int r = tid >> 2, kc = (tid & 3) * 8;
                float4 f0 = *(const float4*)(query + (size_t)(m0 + r) * 256 + k0 + kc);
                float4 f1 = *(const float4*)(query + (size_t)(m0 + r) * 256 + k0 + kc + 4);
                uint4 o;
                o.x = f32_to_bf16(f0.x) | ((unsigned)f32_to_bf16(f0.y) << 16);
                o.y = f32_to_bf16(f0.z) | ((unsigned)f32_to_bf16(f0.w) << 16);
                o.z = f32_to_bf16(f1.x) | ((unsigned)f32_to_bf16(f1.y) << 16);
                o.w = f32_to_bf16(f1.z) | ((unsigned)f32_to_bf16(f1.w) << 16);
                *(uint4*)&As[r][kc] = o;
            }
            #pragma unroll
            for (int i = 0; i < 2; ++i) {           // B: WqT bf16, uint4
                int idx = tid + 256 * i;
                int r = idx >> 2, kc = (idx & 3) * 8;
                *(uint4*)&Bs[r][kc] = *(const uint4*)(WqT + (size_t)(n0 + r) * 256 + k0 + kc);
            }
            __syncthreads();
            bf16x8 af[2], bfr[4];
            #pragma unroll
            for (int mi = 0; mi < 2; ++mi)
                af[mi] = *(const bf16x8*)&As[wm * 32 + mi * 16 + l16][quad * 8];
            #pragma unroll
            for (int ni = 0; ni < 4; ++ni)
                bfr[ni] = *(const bf16x8*)&Bs[wn * 64 + ni * 16 + l16][quad * 8];
            #pragma unroll
            for (int mi = 0; mi < 2; ++mi)
                #pragma unroll
                for (int ni = 0; ni < 4; ++ni)
                    acc[mi][ni] = __builtin_amdgcn_mfma_f32_16x16x32_bf16(
                        af[mi], bfr[ni], acc[mi][ni], 0, 0, 0);
            __syncthreads();
        }

        if (is_attn) {
            #pragma unroll
            for (int mi = 0; mi < 2; ++mi) {
                #pragma unroll
                for (int r = 0; r < 4; ++r) {
                    int gm = m0 + wm * 32 + mi * 16 + quad * 4 + r;
                    #pragma unroll
                    for (int ni = 0; ni < 4; ++ni) {
                        int gn = wn * 64 + ni * 16 + l16;
                        float v = acc[mi][ni][r] + battn[gn];
                        float mx = v;
                        #pragma unroll
                        for (int s = 1; s < 16; s <<= 1)
                            mx = fmaxf(mx, __shfl_xor(mx, s, 64));
                        float e = __expf(v - mx);
                        float sum = e;
                        #pragma unroll
                        for (int s = 1; s < 16; s <<= 1)
                            sum += __shfl_xor(sum, s, 64);
                        qawb[(size_t)gm * 128 + gn] = f32_to_bf16(e / sum);
                    }
                }
            }
        } else {
            #pragma unroll
            for (int mi = 0; mi < 2; ++mi) {
                #pragma unroll
                for (int r = 0; r < 4; ++r) {
                    int gm = m0 + wm * 32 + mi * 16 + quad * 4 + r;
                    #pragma unroll
                    for (int ni = 0; ni < 4; ++ni) {
                        int gn = n0 + wn * 64 + ni * 16 + l16;
                        qoffb[(size_t)gm * 256 + gn] = f32_to_bf16(acc[mi][ni][r] + boff[gn]);
                    }
                }
            }
        }
    }
}

// ---------------------------------------------------------------------------
// sample_kernel: b < 3200 -> head-partitioned fp8 deformable sampling;
// b >= 3200 -> tail weight transpose (Wout/W1/W2 -> WoT/W1T/W2T).
// Cam loop split into 2 phases of 3 cams: s_tab is 13.1 KB so up to 8
// blocks/CU (32 waves) can be resident. NO min-waves launch bound: R2
// showed __launch_bounds__(256,8) forces VGPR=32 and spills ~2.3 GB of
// scratch per dispatch (FETCH 824 MB, WRITE 1.44 GB). Register pressure is
// instead reduced structurally: refpts are re-loaded per phase, not held
// across phases.
// vb channels are interleave-permuted; outsum is written in permuted order
// and WoT's K index is permuted to match (see tail transpose).
// ---------------------------------------------------------------------------
__global__ __launch_bounds__(256) void sample_kernel(
    const unsigned char* __restrict__ vb,  // (6, 8, 7979, 32) fp8 e4m3, ch-permuted
    const unsigned short* __restrict__ qoffb, // (6400, 256) bf16
    const unsigned short* __restrict__ qawb,  // (6400, 128) bf16
    const float* __restrict__ refpts,      // (6, 1, 6400, 4, 2)
    const int*   __restrict__ bev_mask,    // (6, 1, 6400, 4)
    const float* __restrict__ Wout, const float* __restrict__ W1,
    const float* __restrict__ W2,
    unsigned short* __restrict__ outsum,   // (6400, 256) bf16 (ch-permuted)
    float* __restrict__ visb,              // (6400)
    unsigned short* __restrict__ wsT)
{
    __shared__ __align__(16) unsigned s_tab[3][272][4];   // [cam-in-phase][sq*17+tup][corner]
    __shared__ float s_vis[NCAMS][16];
    __shared__ int   s_nvis[16];

    const int bid = blockIdx.x;
    const int tid = threadIdx.x;

    if (bid >= 3200) {
        // ---- tail weight transpose (reuses s_tab as the LDS tile) ----
        int t = bid - 3200;
        const float* src; int K, N, dstoff;
        if (t < 64)       { src = Wout; K = 256;  N = 256;  dstoff = 163840; }
        else if (t < 320) { src = W1;   K = 256;  N = 1024; dstoff = 229376; t -= 64; }
        else              { src = W2;   K = 1024; N = 256;  dstoff = 491520; t -= 320; }
        int ntn = N >> 5;
        int kt = t / ntn, nt = t - kt * ntn;
        float (*tile)[33] = (float(*)[33])&s_tab[0][0][0];
        int tx = tid & 31, ty = tid >> 5;
        #pragma unroll
        for (int i = 0; i < 4; ++i)
            tile[ty + i * 8][tx] = src[(size_t)(kt * 32 + ty + i * 8) * N + nt * 32 + tx];
        __syncthreads();
        // WoT only: permute K index within each 32-channel head block to match
        // the vb/outsum channel interleave: c' = 2*(c&15) | (c>>4)
        int txp = (dstoff == 163840) ? (((tx & 15) << 1) | (tx >> 4)) : tx;
        #pragma unroll
        for (int i = 0; i < 4; ++i) {
            int nn = nt * 32 + ty + i * 8;
            wsT[dstoff + (size_t)nn * K + kt * 32 + txp] = f32_to_bf16(tile[tx][ty + i * 8]);
        }
        return;
    }

    const int h   = bid & 7;
    const int q0  = (bid >> 3) * 16;
    const int sq  = tid >> 4;
    const int tup = tid & 15;
    const int lvl = tup >> 2;
    const int n_s = q0 + sq;

    if (tid < 96) {
        int cam = tid >> 4, q = tid & 15;
        const int* bm = bev_mask + ((size_t)cam * NQ + q0 + q) * 4;
        s_vis[cam][q] = ((bm[0] + bm[1] + bm[2] + bm[3]) > 0) ? 1.f : 0.f;
    }
    __syncthreads();
    if (tid >= 32 && tid < 48) {
        int q = tid - 32;
        float s = 0.f;
        #pragma unroll
        for (int cam = 0; cam < NCAMS; ++cam) s += s_vis[cam][q];
        s_nvis[q] = (int)s;
    }

    unsigned uoff = *(const unsigned*)(qoffb + (size_t)n_s * 256 + h * 32 + tup * 2);
    const float offx  = __uint_as_float(uoff << 16);
    const float offy  = __uint_as_float(uoff & 0xFFFF0000u);
    const float my_aw = __uint_as_float((unsigned)qawb[(size_t)n_s * 128 + h * 16 + tup] << 16);
    const int Wl   = (lvl == 0) ? 100 : (lvl == 1) ? 50 : (lvl == 2) ? 25 : 13;
    const int Hl   = (lvl == 0) ? 60  : (lvl == 1) ? 30 : (lvl == 2) ? 15 : 8;
    const int base = (lvl == 0) ? 0   : (lvl == 1) ? 6000 : (lvl == 2) ? 7500 : 7875;
    const float dx = offx / (float)Wl;
    const float dy = offy / (float)Hl;
    const int tabi = sq * 17 + tup;

    const int tp   = (tid >> 1) & 7;
    const int cg2  = tid & 1;
    const int cg16 = cg2 * 16;

    f32x2 A[8] = {};

    #pragma unroll
    for (int ph = 0; ph < 2; ++ph) {
        // ---- build sampling tables for cams [ph*3, ph*3+3) ----
        #pragma unroll
        for (int kk = 0; kk < 3; ++kk) {
            int k = ph * 3 + kk;
            float2 rpk = *(const float2*)(refpts + (((size_t)k * NQ + n_s) * 4 + lvl) * 2);
            float fx = (rpk.x + dx) * (float)Wl - 0.5f;
            float fy = (rpk.y + dy) * (float)Hl - 0.5f;
            float x0f = floorf(fx), y0f = floorf(fy);
            float lx = fx - x0f, ly = fy - y0f;
            int x0 = (int)x0f, y0 = (int)y0f;
            int x1 = x0 + 1, y1 = y0 + 1;
            float wb = my_aw * s_vis[k][sq];
            float w00 = (1.f - lx) * (1.f - ly) * wb;
            float w01 = lx * (1.f - ly) * wb;
            float w10 = (1.f - lx) * ly * wb;
            float w11 = lx * ly * wb;
            bool vx0 = (x0 >= 0) & (x0 < Wl), vx1 = (x1 >= 0) & (x1 < Wl);
            bool vy0 = (y0 >= 0) & (y0 < Hl), vy1 = (y1 >= 0) & (y1 < Hl);
            uint4 o;
            o.x = (vx0 & vy0) ? (((unsigned)(base + y0 * Wl + x0) << 16) | f32_to_bf16(w00)) : 0u;
            o.y = (vx1 & vy0) ? (((unsigned)(base + y0 * Wl + x1) << 16) | f32_to_bf16(w01)) : 0u;
            o.z = (vx0 & vy1) ? (((unsigned)(base + y1 * Wl + x0) << 16) | f32_to_bf16(w10)) : 0u;
            o.w = (vx1 & vy1) ? (((unsigned)(base + y1 * Wl + x1) << 16) | f32_to_bf16(w11)) : 0u;
            *(uint4*)&s_tab[kk][tabi][0] = o;
        }
        __syncthreads();

        // ---- accumulate cams [ph*3, ph*3+3) ----
        #pragma unroll
        for (int kk = 0; kk < 3; ++kk) {
            int k = ph * 3 + kk;
            const unsigned char* vkh =            // wave-uniform slice base
                vb + (size_t)((k * 8 + h) * (LTOT * 32));
            #pragma unroll
            for (int t = 0; t < 2; ++t) {
                uint4 t4 = *(const uint4*)&s_tab[kk][sq * 17 + tp * 2 + t][0];
                #pragma unroll
                for (int corner = 0; corner < 4; ++corner) {
                    unsigned tc = (corner == 0) ? t4.x : (corner == 1) ? t4.y
                                : (corner == 2) ? t4.z : t4.w;
                    float w = __uint_as_float(tc << 16);
                    f32x2 w2 = {w, w};
                    int off = (int)((tc >> 16) << 5) + cg16;   // 32-bit lane offset
                    uint4 d = *(const uint4*)(vkh + off);
                    A[0] += w2 * __builtin_amdgcn_cvt_pk_f32_fp8(d.x, false);
                    A[1] += w2 * __builtin_amdgcn_cvt_pk_f32_fp8(d.x, true);
                    A[2] += w2 * __builtin_amdgcn_cvt_pk_f32_fp8(d.y, false);
                    A[3] += w2 * __builtin_amdgcn_cvt_pk_f32_fp8(d.y, true);
                    A[4] += w2 * __builtin_amdgcn_cvt_pk_f32_fp8(d.z, false);
                    A[5] += w2 * __builtin_amdgcn_cvt_pk_f32_fp8(d.z, true);
                    A[6] += w2 * __builtin_amdgcn_cvt_pk_f32_fp8(d.w, false);
                    A[7] += w2 * __builtin_amdgcn_cvt_pk_f32_fp8(d.w, true);
                }
            }
        }
        __syncthreads();   // table buffer reused by next phase
    }

    // reduce across the 8 tap-threads (lane bits 1..3)
    #pragma unroll
    for (int i = 0; i < 8; ++i) {
        float x0 = A[i].x, x1 = A[i].y;
        x0 += __shfl_xor(x0, 2, 64); x1 += __shfl_xor(x1, 2, 64);
        x0 += __shfl_xor(x0, 4, 64); x1 += __shfl_xor(x1, 4, 64);
        x0 += __shfl_xor(x0, 8, 64); x1 += __shfl_xor(x1, 8, 64);
        A[i].x = x0; A[i].y = x1;
    }

    if ((tid & 14) == 0) {          // tp == 0: two writers per query (cg2 = 0,1)
        int nv = s_nvis[sq];
        float sc = 1.f / (float)(nv > 0 ? nv : 1);
        uint4 o0, o1;
        o0.x = f32_to_bf16(A[0].x * sc) | ((unsigned)f32_to_bf16(A[0].y * sc) << 16);
        o0.y = f32_to_bf16(A[1].x * sc) | ((unsigned)f32_to_bf16(A[1].y * sc) << 16);
        o0.z = f32_to_bf16(A[2].x * sc) | ((unsigned)f32_to_bf16(A[2].y * sc) << 16);
        o0.w = f32_to_bf16(A[3].x * sc) | ((unsigned)f32_to_bf16(A[3].y * sc) << 16);
        o1.x = f32_to_bf16(A[4].x * sc) | ((unsigned)f32_to_bf16(A[4].y * sc) << 16);
        o1.y = f32_to_bf16(A[5].x * sc) | ((unsigned)f32_to_bf16(A[5].y * sc) << 16);
        o1.z = f32_to_bf16(A[6].x * sc) | ((unsigned)f32_to_bf16(A[6].y * sc) << 16);
        o1.w = f32_to_bf16(A[7].x * sc) | ((unsigned)f32_to_bf16(A[7].y * sc) << 16);
        *(uint4*)(outsum + (size_t)n_s * 256 + h * 32 + cg2 * 16)     = o0;
        *(uint4*)(outsum + (size_t)n_s * 256 + h * 32 + cg2 * 16 + 8) = o1;
    }
    if (h == 0 && tid < 16) visb[q0 + tid] = (s_nvis[tid] > 0) ? 1.f : 0.f;
}

// ---------------------------------------------------------------------------
// Fused output-projection + residual + LN1 (phase-1 only of the old fused
// kernel; FFN1 moved to a wide gemm64 launch for occupancy).
// BM=32 BN=256 K=256: x = LN(outsum@WoT + residual algebra), written to
// xout (fp32, for LN2) and xb16 (bf16, A-operand of FFN1).
// ---------------------------------------------------------------------------
__global__ __launch_bounds__(256) void projln1_kernel(
    const unsigned short* __restrict__ A, const unsigned short* __restrict__ BT,
    const float* __restrict__ query, const float* __restrict__ visb,
    const float* __restrict__ b_out, const float* __restrict__ g,
    const float* __restrict__ b,
    float* __restrict__ xout, unsigned short* __restrict__ xb16)
{
    const int K = 256;
    __shared__ __align__(16) unsigned short As[32][40];
    __shared__ __align__(16) unsigned short Bs[256][40];
    __shared__ float sred[2][4][4][2];
    __shared__ float ssred[2][4][4][2];
    __shared__ float s_mu[32], s_rs[32];

    const int tid  = threadIdx.x;
    const int wave = tid >> 6, lane = tid & 63;
    const int wm = wave >> 1, wn = wave & 1;
    const int quad = lane >> 4, l16 = lane & 15;
    const int m0 = blockIdx.x * 32;

    f32x4 acc[8] = {};

    for (int k0 = 0; k0 < K; k0 += 32) {
        {
            int r = tid >> 3, kc = (tid & 7) * 4;
            *(uint2*)&As[r][kc] = *(const uint2*)(A + (size_t)(m0 + r) * K + k0 + kc);
        }
        {
            const unsigned short* src = BT + (size_t)tid * K + k0;
            *(uint4*)&Bs[tid][0]  = *(const uint4*)(src);
            *(uint4*)&Bs[tid][8]  = *(const uint4*)(src + 8);
            *(uint4*)&Bs[tid][16] = *(const uint4*)(src + 16);
            *(uint4*)&Bs[tid][24] = *(const uint4*)(src + 24);
        }
        __syncthreads();
        bf16x8 af = *(const bf16x8*)&As[wm * 16 + l16][quad * 8];
        #pragma unroll
        for (int ni = 0; ni < 8; ++ni) {
            bf16x8 bfr = *(const bf16x8*)&Bs[wn * 128 + ni * 16 + l16][quad * 8];
            acc[ni] = __builtin_amdgcn_mfma_f32_16x16x32_bf16(af, bfr, acc[ni], 0, 0, 0);
        }
        __syncthreads();
    }

    float vals[8][4];
    #pragma unroll
    for (int r = 0; r < 4; ++r) {
        int gm = m0 + wm * 16 + quad * 4 + r;
        float vs = visb[gm];
        float s = 0.f, ss = 0.f;
        #pragma unroll
        for (int ni = 0; ni < 8; ++ni) {
            int gn = wn * 128 + ni * 16 + l16;
            float v = acc[ni][r] + vs * b_out[gn]
                    + query[(size_t)gm * 256 + gn] * (1.f + vs);
            vals[ni][r] = v;
            s += v; ss += v * v;
        }
        #pragma unroll
        for (int m = 1; m < 16; m <<= 1) {
            s  += __shfl_xor(s,  m, 64);
            ss += __shfl_xor(ss, m, 64);
        }
        if (l16 == 0) {
            sred[wm][quad][r][wn]  = s;
            ssred[wm][quad][r][wn] = ss;
        }
    }
    __syncthreads();
    if (tid < 32) {
        int lwm = tid >> 4, lq = (tid >> 2) & 3, lr = tid & 3;
        float s  = sred[lwm][lq][lr][0]  + sred[lwm][lq][lr][1];
        float ss = ssred[lwm][lq][lr][0] + ssred[lwm][lq][lr][1];
        float mu = s * (1.f / 256.f);
        float var = ss * (1.f / 256.f) - mu * mu;
        s_mu[tid] = mu;
        s_rs[tid] = rsqrtf(var + 1e-5f);
    }
    __syncthreads();

    #pragma unroll
    for (int r = 0; r < 4; ++r) {
        int rowl = wm * 16 + quad * 4 + r;
        int gm = m0 + rowl;
        float mu = s_mu[rowl], rs = s_rs[rowl];
        #pragma unroll
        for (int ni = 0; ni < 8; ++ni) {
            int gn = wn * 128 + ni * 16 + l16;
            float res = (vals[ni][r] - mu) * rs * g[gn] + b[gn];
            xout[(size_t)gm * 256 + gn] = res;
            xb16[(size_t)gm * 256 + gn] = f32_to_bf16(res);
        }
    }
}

// ---------------------------------------------------------------------------
// MFMA bf16 GEMM, BM=64 BN=128 BK=32, bf16 A + BT. Split-K over gridDim.z.
// mode 1: relu -> bf16 out; mode 2: plain bf16 out (split-K partials).
// ---------------------------------------------------------------------------
__global__ __launch_bounds__(256) void gemm64_kernel(
    const unsigned short* __restrict__ A, const unsigned short* __restrict__ BT,
    const float* __restrict__ bias, unsigned short* __restrict__ Cb,
    int M, int N, int K, int mode)
{
    __shared__ __align__(16) unsigned short As[64][40];
    __shared__ __align__(16) unsigned short Bs[128][40];

    const int tid  = threadIdx.x;
    const int wave = tid >> 6, lane = tid & 63;
    const int wm = wave >> 1, wn = wave & 1;
    const int quad = lane >> 4, l16 = lane & 15;
    const int m0 = blockIdx.y * 64, n0 = blockIdx.x * 128;
    const int nz = gridDim.z;
    const int klen = K / nz;
    const int kbase = blockIdx.z * klen;

    f32x4 acc[2][4] = {};

    for (int k0 = kbase; k0 < kbase + klen; k0 += 32) {
        {
            int r = tid >> 2, kc = (tid & 3) * 8;
            int gr = m0 + r;
            uint4 d = (gr < M) ? *(const uint4*)(A + (size_t)gr * K + k0 + kc)
                               : make_uint4(0u, 0u, 0u, 0u);
            *(uint4*)&As[r][kc] = d;
        }
        #pragma unroll
        for (int i = 0; i < 2; ++i) {
            int idx = tid + 256 * i;
            int r = idx >> 2, kc = (idx & 3) * 8;
            *(uint4*)&Bs[r][kc] = *(const uint4*)(BT + (size_t)(n0 + r) * K + k0 + kc);
        }
        __syncthreads();
        bf16x8 af[2], bfr[4];
        #pragma unroll
        for (int mi = 0; mi < 2; ++mi)
            af[mi] = *(const bf16x8*)&As[wm * 32 + mi * 16 + l16][quad * 8];
        #pragma unroll
        for (int ni = 0; ni < 4; ++ni)
            bfr[ni] = *(const bf16x8*)&Bs[wn * 64 + ni * 16 + l16][quad * 8];
        #pragma unroll
        for (int mi = 0; mi < 2; ++mi)
            #pragma unroll
            for (int ni = 0; ni < 4; ++ni)
                acc[mi][ni] = __builtin_amdgcn_mfma_f32_16x16x32_bf16(
                    af[mi], bfr[ni], acc[mi][ni], 0, 0, 0);
        __syncthreads();
    }

    const float* bz = (blockIdx.z == 0) ? bias : nullptr;
    unsigned short* Cz = Cb + (size_t)blockIdx.z * M * N;

    #pragma unroll
    for (int mi = 0; mi < 2; ++mi) {
        #pragma unroll
        for (int r = 0; r < 4; ++r) {
            int gm = m0 + wm * 32 + mi * 16 + quad * 4 + r;
            if (gm >= M) continue;
            #pragma unroll
            for (int ni = 0; ni < 4; ++ni) {
                int gn = n0 + wn * 64 + ni * 16 + l16;
                float v = acc[mi][ni][r] + (bz ? bz[gn] : 0.f);
                if (mode == 1) v = fmaxf(v, 0.f);
                Cz[(size_t)gm * N + gn] = f32_to_bf16(v);
            }
        }
    }
}

// ---------------------------------------------------------------------------
// Vectorized LN2: one wave per row; x fp32 + two bf16 split-K halves.
// ---------------------------------------------------------------------------
__global__ __launch_bounds__(256) void ln2v_kernel(
    const float* __restrict__ x, const unsigned short* __restrict__ f0,
    const unsigned short* __restrict__ f1,
    const float* __restrict__ g, const float* __restrict__ b,
    float* __restrict__ out)
{
    int row  = blockIdx.x * 4 + (threadIdx.x >> 6);
    int lane = threadIdx.x & 63;
    size_t base = (size_t)row * 256 + lane * 4;
    float4 xv = *(const float4*)(x + base);
    uint2 u0 = *(const uint2*)(f0 + base);
    uint2 u1 = *(const uint2*)(f1 + base);
    float t0 = xv.x + __uint_as_float(u0.x << 16)        + __uint_as_float(u1.x << 16);
    float t1 = xv.y + __uint_as_float(u0.x & 0xFFFF0000u) + __uint_as_float(u1.x & 0xFFFF0000u);
    float t2 = xv.z + __uint_as_float(u0.y << 16)        + __uint_as_float(u1.y << 16);
    float t3 = xv.w + __uint_as_float(u0.y & 0xFFFF0000u) + __uint_as_float(u1.y & 0xFFFF0000u);
    float s  = t0 + t1 + t2 + t3;
    float ss = t0 * t0 + t1 * t1 + t2 * t2 + t3 * t3;
    #pragma unroll
    for (int m = 1; m < 64; m <<= 1) {
        s  += __shfl_xor(s,  m, 64);
        ss += __shfl_xor(ss, m, 64);
    }
    float mu = s * (1.f / 256.f);
    float rs = rsqrtf(ss * (1.f / 256.f) - mu * mu + 1e-5f);
    float4 gv = *(const float4*)(g + lane * 4);
    float4 bv = *(const float4*)(b + lane * 4);
    float4 o;
    o.x = (t0 - mu) * rs * gv.x + bv.x;
    o.y = (t1 - mu) * rs * gv.y + bv.y;
    o.z = (t2 - mu) * rs * gv.z + bv.z;
    o.w = (t3 - mu) * rs * gv.w + bv.w;
    *(float4*)(out + base) = o;
}

// ---------------------------------------------------------------------------
extern "C" void kernel_launch(void* const* d_in, const int* in_sizes, int n_in,
                              void* d_out, int out_size, void* d_ws, size_t ws_size,
                              hipStream_t stream)
{
    const float* query   = (const float*)d_in[0];
    const float* value   = (const float*)d_in[2];
    const float* refpts  = (const float*)d_in[3];
    const int*   bevmask = (const int*)d_in[6];
    const float* W_value = (const float*)d_in[7];
    const float* b_value = (const float*)d_in[8];
    const float* W_off   = (const float*)d_in[9];
    const float* b_off   = (const float*)d_in[10];
    const float* W_attn  = (const float*)d_in[11];
    const float* b_attn  = (const float*)d_in[12];
    const float* W_out   = (const float*)d_in[13];
    const float* b_out   = (const float*)d_in[14];
    const float* ln1_g   = (const float*)d_in[15];
    const float* ln1_b   = (const float*)d_in[16];
    const float* W1      = (const float*)d_in[17];
    const float* b1      = (const float*)d_in[18];
    const float* W2      = (const float*)d_in[19];
    const float* b2      = (const float*)d_in[20];
    const float* ln2_g   = (const float*)d_in[21];
    const float* ln2_b   = (const float*)d_in[22];
    float* out = (float*)d_out;

    // workspace layout (byte offsets, temporal aliasing):
    //  [0)          vb fp8 12,255,744       (head -> sample)
    //  [0)          xbuf fp32 6,553,600     (projln1 -> ln2) [vb dead]
    //  [13,000,000) hbf bf16 13,107,200     (ffn1 -> ffn2)
    //  [27,000,000) qoffb bf16 3,276,800    (head -> sample)
    //  [27,000,000) xb16 bf16 3,276,800     (projln1 -> ffn1) [qoffb dead]
    //  [31,000,000) qawb bf16 1,638,400     (head -> sample)
    //  [33,000,000) outsum bf16 3,276,800   (sample -> projln1)
    //  [36,500,000) visb 25,600             (sample -> projln1)
    //  [36,600,000) wsT bf16 1,507,328      (wt_head/sample-tail -> GEMMs)
    //  [39,000,000) ffnout bf16 2x3,276,800 (ffn2 -> ln2)
    char* ws = (char*)d_ws;
    unsigned char*  vb     = (unsigned char*)(ws + 0);
    float*          xbuf   = (float*)(ws + 0);
    unsigned short* hbf    = (unsigned short*)(ws + 13000000);
    unsigned short* qoffb  = (unsigned short*)(ws + 27000000);
    unsigned short* xb16   = (unsigned short*)(ws + 27000000);
    unsigned short* qawb   = (unsigned short*)(ws + 31000000);
    unsigned short* outsum = (unsigned short*)(ws + 33000000);
    float*          visb   = (float*)(ws + 36500000);
    unsigned short* wsT    = (unsigned short*)(ws + 36600000);
    unsigned short* ffnout = (unsigned short*)(ws + 39000000);

    unsigned short* WvT = wsT;            // [256][256]
    unsigned short* WqT = wsT + 65536;    // [384][256]
    unsigned short* WoT = wsT + 163840;   // [256][256] (K-permuted)
    unsigned short* W1T = wsT + 229376;   // [1024][256]
    unsigned short* W2T = wsT + 491520;   // [256][1024]

    // L0: head-side weights -> transposed bf16 (160 blocks)
    wt_head_kernel<<<dim3(160), 256, 0, stream>>>(
        W_value, W_off, W_attn, wsT);
    // L1: value proj (750 blocks, fp8 out, ch-permuted) + query proj (300 blocks)
    head_kernel<<<dim3(1050), 256, 0, stream>>>(
        value, query, WvT, WqT, b_value, b_off, b_attn, vb, qoffb, qawb);
    // L2: sampling (3200) + tail weight transpose (576, overlapped)
    sample_kernel<<<dim3(3776), 256, 0, stream>>>(
        vb, qoffb, qawb, refpts, bevmask, W_out, W1, W2, outsum, visb, wsT);
    // L3: x = LN(outsum@WoT + residual) -> xbuf fp32 + xb16 bf16
    projln1_kernel<<<dim3(200), 256, 0, stream>>>(
        outsum, WoT, query, visb, b_out, ln1_g, ln1_b, xbuf, xb16);
    // L4: h = relu(xb16 @ W1 + b1), 800 blocks
    gemm64_kernel<<<dim3(8, 100, 1), 256, 0, stream>>>(
        xb16, W1T, b1, hbf, NQ, DFFN, 256, 1);
    // L5: ffnout[z] = bf16(h @ W2 (+b2 on z=0)), split-K x2
    gemm64_kernel<<<dim3(2, 100, 2), 256, 0, stream>>>(
        hbf, W2T, b2, ffnout, NQ, 256, DFFN, 2);
    // L6: out = LN(x + f0 + f1)
    ln2v_kernel<<<dim3(1600), 256, 0, stream>>>(
        xbuf, ffnout, ffnout + (size_t)NQ * 256, ln2_g, ln2_b, out);
}

// Round 4
// 300.965 us; speedup vs baseline: 3.1291x; 1.1534x over previous
//
#include <hip/hip_runtime.h>
#include <math.h>

#define NQ      6400
#define NCAMS   6
#define LTOT    7979
#define DM      256
#define DFFN    1024

typedef __attribute__((ext_vector_type(8))) short bf16x8;
typedef __attribute__((ext_vector_type(4))) float f32x4;
typedef __attribute__((ext_vector_type(2))) float f32x2;

__device__ inline unsigned short f32_to_bf16(float f) {
    unsigned u = __float_as_uint(f);
    unsigned r = u + 0x7FFF + ((u >> 16) & 1);   // round-to-nearest-even
    return (unsigned short)(r >> 16);
}

// ---------------------------------------------------------------------------
// wt_head: transpose+convert only the weights the head kernel needs.
// wsT layout (shorts): WvT@0, WqT@65536 ([384][256]). 160 blocks.
// ---------------------------------------------------------------------------
__global__ __launch_bounds__(256) void wt_head_kernel(
    const float* __restrict__ Wv, const float* __restrict__ Woff,
    const float* __restrict__ Wattn, unsigned short* __restrict__ wsT)
{
    int b = blockIdx.x;
    const float* src; int K, N, t0, dstoff;
    if (b < 64)       { src = Wv;    K = 256; N = 256; t0 = 0;   dstoff = 0; }
    else if (b < 128) { src = Woff;  K = 256; N = 256; t0 = 64;  dstoff = 65536; }
    else              { src = Wattn; K = 256; N = 128; t0 = 128; dstoff = 131072; }
    int t = b - t0;
    int ntn = N >> 5;
    int kt = t / ntn, nt = t - kt * ntn;
    __shared__ float tile[32][33];
    int tx = threadIdx.x & 31, ty = threadIdx.x >> 5;
    #pragma unroll
    for (int i = 0; i < 4; ++i)
        tile[ty + i * 8][tx] = src[(size_t)(kt * 32 + ty + i * 8) * N + nt * 32 + tx];
    __syncthreads();
    #pragma unroll
    for (int i = 0; i < 4; ++i) {
        int nn = nt * 32 + ty + i * 8;
        wsT[dstoff + (size_t)nn * K + kt * 32 + tx] = f32_to_bf16(tile[tx][ty + i * 8]);
    }
}

// ---------------------------------------------------------------------------
// head_kernel: merged value projection + query projections.
//  b <  750 : value proj (BM=BN=128) -> vb FP8 e4m3 head-major
//             (cam, head, pixel, 32ch PERMUTED c' = 2*(c&15)+(c>>4)), 32 B rows.
//             Channel interleave lets each lane pack 2 fp8 per ushort store.
//  else     : query projections (BM=64): bx=0,1 -> qoff (bf16);
//             bx=2 -> softmax -> qaw (bf16)
// ---------------------------------------------------------------------------
__global__ __launch_bounds__(256) void head_kernel(
    const float* __restrict__ value, const float* __restrict__ query,
    const unsigned short* __restrict__ WvT, const unsigned short* __restrict__ WqT,
    const float* __restrict__ bv, const float* __restrict__ boff,
    const float* __restrict__ battn,
    unsigned char* __restrict__ vb, unsigned short* __restrict__ qoffb,
    unsigned short* __restrict__ qawb)
{
    __shared__ __align__(16) unsigned char smem[20480];
    const int b = blockIdx.x;
    const int tid = threadIdx.x;
    const int wave = tid >> 6, lane = tid & 63;
    const int wm = wave >> 1, wn = wave & 1;
    const int quad = lane >> 4, l16 = lane & 15;

    if (b < 750) {
        unsigned short (*As)[40] = (unsigned short(*)[40])smem;
        unsigned short (*Bs)[40] = (unsigned short(*)[40])(smem + 10240);
        const int m0 = (b >> 1) * 128, n0 = (b & 1) * 128;
        const int M = NCAMS * LTOT;

        f32x4 acc[4][4] = {};

        for (int k0 = 0; k0 < 256; k0 += 32) {
            #pragma unroll
            for (int i = 0; i < 2; ++i) {          // A: 128x32 fp32 -> bf16
                int idx = tid + 256 * i;
                int r = idx >> 2, kc = (idx & 3) * 8;
                int gr = m0 + r;
                float4 f0, f1;
                if (gr < M) {
                    f0 = *(const float4*)(value + (size_t)gr * 256 + k0 + kc);
                    f1 = *(const float4*)(value + (size_t)gr * 256 + k0 + kc + 4);
                } else { f0 = make_float4(0.f,0.f,0.f,0.f); f1 = f0; }
                uint4 o;
                o.x = f32_to_bf16(f0.x) | ((unsigned)f32_to_bf16(f0.y) << 16);
                o.y = f32_to_bf16(f0.z) | ((unsigned)f32_to_bf16(f0.w) << 16);
                o.z = f32_to_bf16(f1.x) | ((unsigned)f32_to_bf16(f1.y) << 16);
                o.w = f32_to_bf16(f1.z) | ((unsigned)f32_to_bf16(f1.w) << 16);
                *(uint4*)&As[r][kc] = o;
            }
            #pragma unroll
            for (int i = 0; i < 2; ++i) {          // B: WvT bf16, uint4
                int idx = tid + 256 * i;
                int r = idx >> 2, kc = (idx & 3) * 8;
                *(uint4*)&Bs[r][kc] = *(const uint4*)(WvT + (size_t)(n0 + r) * 256 + k0 + kc);
            }
            __syncthreads();
            bf16x8 af[4], bfr[4];
            #pragma unroll
            for (int mi = 0; mi < 4; ++mi)
                af[mi] = *(const bf16x8*)&As[wm * 64 + mi * 16 + l16][quad * 8];
            #pragma unroll
            for (int ni = 0; ni < 4; ++ni)
                bfr[ni] = *(const bf16x8*)&Bs[wn * 64 + ni * 16 + l16][quad * 8];
            #pragma unroll
            for (int mi = 0; mi < 4; ++mi)
                #pragma unroll
                for (int ni = 0; ni < 4; ++ni)
                    acc[mi][ni] = __builtin_amdgcn_mfma_f32_16x16x32_bf16(
                        af[mi], bfr[ni], acc[mi][ni], 0, 0, 0);
            __syncthreads();
        }

        // epilogue: pack channel pairs (c, c+16) -> adjacent bytes (2c', 2c'+1)
        #pragma unroll
        for (int mi = 0; mi < 4; ++mi) {
            #pragma unroll
            for (int r = 0; r < 4; ++r) {
                int gm = m0 + wm * 64 + mi * 16 + quad * 4 + r;
                if (gm >= M) continue;
                int cam = gm / LTOT;
                int pix = gm - cam * LTOT;
                #pragma unroll
                for (int p = 0; p < 2; ++p) {
                    int gn0 = n0 + wn * 64 + p * 32 + l16;   // c = l16 (mod 32)
                    int head = gn0 >> 5;
                    float v0 = acc[mi][2 * p][r]     + bv[gn0];
                    float v1 = acc[mi][2 * p + 1][r] + bv[gn0 + 16];
                    int pk = __builtin_amdgcn_cvt_pk_fp8_f32(v0, v1, 0, false);
                    *(unsigned short*)(vb + (((size_t)(cam * 8 + head)) * LTOT + pix) * 32
                                       + 2 * l16) = (unsigned short)pk;
                }
            }
        }
    } else {
        unsigned short (*As)[40] = (unsigned short(*)[40])smem;
        unsigned short (*Bs)[40] = (unsigned short(*)[40])(smem + 5120);
        const int t = b - 750;
        const int bx = t / 100, by = t % 100;
        const int m0 = by * 64, n0 = bx * 128;
        const int is_attn = (bx == 2);

        f32x4 acc[2][4] = {};

        for (int k0 = 0; k0 < 256; k0 += 32) {
            {                                       // A: 64x32 fp32 -> bf16
                int r = tid >> 2, kc = (tid & 3) * 8;
                float4 f0 = *(const float4*)(query + (size_t)(m0 + r) * 256 + k0 + kc);
                float4 f1 = *(const float4*)(query + (size_t)(m0 + r) * 256 + k0 + kc + 4);
                uint4 o;
                o.x = f32_to_bf16(f0.x) | ((unsigned)f32_to_bf16(f0.y) << 16);
                o.y = f32_to_bf16(f0.z) | ((unsigned)f32_to_bf16(f0.w) << 16);
                o.z = f32_to_bf16(f1.x) | ((unsigned)f32_to_bf16(f1.y) << 16);
                o.w = f32_to_bf16(f1.z) | ((unsigned)f32_to_bf16(f1.w) << 16);
                *(uint4*)&As[r][kc] = o;
            }
            #pragma unroll
            for (int i = 0; i < 2; ++i) {           // B: WqT bf16, uint4
                int idx = tid + 256 * i;
                int r = idx >> 2, kc = (idx & 3) * 8;
                *(uint4*)&Bs[r][kc] = *(const uint4*)(WqT + (size_t)(n0 + r) * 256 + k0 + kc);
            }
            __syncthreads();
            bf16x8 af[2], bfr[4];
            #pragma unroll
            for (int mi = 0; mi < 2; ++mi)
                af[mi] = *(const bf16x8*)&As[wm * 32 + mi * 16 + l16][quad * 8];
            #pragma unroll
            for (int ni = 0; ni < 4; ++ni)
                bfr[ni] = *(const bf16x8*)&Bs[wn * 64 + ni * 16 + l16][quad * 8];
            #pragma unroll
            for (int mi = 0; mi < 2; ++mi)
                #pragma unroll
                for (int ni = 0; ni < 4; ++ni)
                    acc[mi][ni] = __builtin_amdgcn_mfma_f32_16x16x32_bf16(
                        af[mi], bfr[ni], acc[mi][ni], 0, 0, 0);
            __syncthreads();
        }

        if (is_attn) {
            #pragma unroll
            for (int mi = 0; mi < 2; ++mi) {
                #pragma unroll
                for (int r = 0; r < 4; ++r) {
                    int gm = m0 + wm * 32 + mi * 16 + quad * 4 + r;
                    #pragma unroll
                    for (int ni = 0; ni < 4; ++ni) {
                        int gn = wn * 64 + ni * 16 + l16;
                        float v = acc[mi][ni][r] + battn[gn];
                        float mx = v;
                        #pragma unroll
                        for (int s = 1; s < 16; s <<= 1)
                            mx = fmaxf(mx, __shfl_xor(mx, s, 64));
                        float e = __expf(v - mx);
                        float sum = e;
                        #pragma unroll
                        for (int s = 1; s < 16; s <<= 1)
                            sum += __shfl_xor(sum, s, 64);
                        qawb[(size_t)gm * 128 + gn] = f32_to_bf16(e / sum);
                    }
                }
            }
        } else {
            #pragma unroll
            for (int mi = 0; mi < 2; ++mi) {
                #pragma unroll
                for (int r = 0; r < 4; ++r) {
                    int gm = m0 + wm * 32 + mi * 16 + quad * 4 + r;
                    #pragma unroll
                    for (int ni = 0; ni < 4; ++ni) {
                        int gn = n0 + wn * 64 + ni * 16 + l16;
                        qoffb[(size_t)gm * 256 + gn] = f32_to_bf16(acc[mi][ni][r] + boff[gn]);
                    }
                }
            }
        }
    }
}

// ---------------------------------------------------------------------------
// sample_kernel: b < 3200 -> head-partitioned fp8 deformable sampling;
// b >= 3200 -> tail weight transpose (Wout/W1/W2 -> WoT/W1T/W2T).
// The 24 KB LDS sampling table is GONE: each thread keeps its own tuple's
// corner entries in registers (tab[6]); the gather phase needs only the
// adjacent lane's entries (tup == 2*tp + cg2), fetched with __shfl_xor(.,1)
// (quad-perm DPP, pure VALU). Tuple-pair accumulation is commutative so no
// selects are needed. LDS drops to ~5 KB -> residency becomes wave-slot
// limited (8 blocks/CU). Instruction structure otherwise identical to the
// verified 47.8 us version (R2/R3 lesson: don't restructure the schedule,
// don't clamp registers with launch bounds).
// vb channels are interleave-permuted; outsum is written in permuted order
// and WoT's K index is permuted to match (see tail transpose).
// ---------------------------------------------------------------------------
__global__ __launch_bounds__(256) void sample_kernel(
    const unsigned char* __restrict__ vb,  // (6, 8, 7979, 32) fp8 e4m3, ch-permuted
    const unsigned short* __restrict__ qoffb, // (6400, 256) bf16
    const unsigned short* __restrict__ qawb,  // (6400, 128) bf16
    const float* __restrict__ refpts,      // (6, 1, 6400, 4, 2)
    const int*   __restrict__ bev_mask,    // (6, 1, 6400, 4)
    const float* __restrict__ Wout, const float* __restrict__ W1,
    const float* __restrict__ W2,
    unsigned short* __restrict__ outsum,   // (6400, 256) bf16 (ch-permuted)
    float* __restrict__ visb,              // (6400)
    unsigned short* __restrict__ wsT)
{
    __shared__ __align__(16) float s_tile[32][33];   // tail transpose only
    __shared__ float s_vis[NCAMS][16];
    __shared__ int   s_nvis[16];

    const int bid = blockIdx.x;
    const int tid = threadIdx.x;

    if (bid >= 3200) {
        // ---- tail weight transpose ----
        int t = bid - 3200;
        const float* src; int K, N, dstoff;
        if (t < 64)       { src = Wout; K = 256;  N = 256;  dstoff = 163840; }
        else if (t < 320) { src = W1;   K = 256;  N = 1024; dstoff = 229376; t -= 64; }
        else              { src = W2;   K = 1024; N = 256;  dstoff = 491520; t -= 320; }
        int ntn = N >> 5;
        int kt = t / ntn, nt = t - kt * ntn;
        int tx = tid & 31, ty = tid >> 5;
        #pragma unroll
        for (int i = 0; i < 4; ++i)
            s_tile[ty + i * 8][tx] = src[(size_t)(kt * 32 + ty + i * 8) * N + nt * 32 + tx];
        __syncthreads();
        // WoT only: permute K index within each 32-channel head block to match
        // the vb/outsum channel interleave: c' = 2*(c&15) | (c>>4)
        int txp = (dstoff == 163840) ? (((tx & 15) << 1) | (tx >> 4)) : tx;
        #pragma unroll
        for (int i = 0; i < 4; ++i) {
            int nn = nt * 32 + ty + i * 8;
            wsT[dstoff + (size_t)nn * K + kt * 32 + txp] = f32_to_bf16(s_tile[tx][ty + i * 8]);
        }
        return;
    }

    const int h   = bid & 7;
    const int q0  = (bid >> 3) * 16;
    const int sq  = tid >> 4;
    const int tup = tid & 15;
    const int lvl = tup >> 2;
    const int n_s = q0 + sq;

    if (tid < 96) {
        int cam = tid >> 4, q = tid & 15;
        const int* bm = bev_mask + ((size_t)cam * NQ + q0 + q) * 4;
        s_vis[cam][q] = ((bm[0] + bm[1] + bm[2] + bm[3]) > 0) ? 1.f : 0.f;
    }
    __syncthreads();
    if (tid >= 32 && tid < 48) {
        int q = tid - 32;
        float s = 0.f;
        #pragma unroll
        for (int cam = 0; cam < NCAMS; ++cam) s += s_vis[cam][q];
        s_nvis[q] = (int)s;
    }

    unsigned uoff = *(const unsigned*)(qoffb + (size_t)n_s * 256 + h * 32 + tup * 2);
    const float offx  = __uint_as_float(uoff << 16);
    const float offy  = __uint_as_float(uoff & 0xFFFF0000u);
    const float my_aw = __uint_as_float((unsigned)qawb[(size_t)n_s * 128 + h * 16 + tup] << 16);
    const int Wl   = (lvl == 0) ? 100 : (lvl == 1) ? 50 : (lvl == 2) ? 25 : 13;
    const int Hl   = (lvl == 0) ? 60  : (lvl == 1) ? 30 : (lvl == 2) ? 15 : 8;
    const int base = (lvl == 0) ? 0   : (lvl == 1) ? 6000 : (lvl == 2) ? 7500 : 7875;
    const float dx = offx / (float)Wl;
    const float dy = offy / (float)Hl;

    const int tp   = (tid >> 1) & 7;   (void)tp;
    const int cg2  = tid & 1;
    const int cg16 = cg2 * 16;

    // ---- build this thread's tuple table for all 6 cams (registers) ----
    uint4 tab[NCAMS];
    #pragma unroll
    for (int k = 0; k < NCAMS; ++k) {
        float2 rpk = *(const float2*)(refpts + (((size_t)k * NQ + n_s) * 4 + lvl) * 2);
        float fx = (rpk.x + dx) * (float)Wl - 0.5f;
        float fy = (rpk.y + dy) * (float)Hl - 0.5f;
        float x0f = floorf(fx), y0f = floorf(fy);
        float lx = fx - x0f, ly = fy - y0f;
        int x0 = (int)x0f, y0 = (int)y0f;
        int x1 = x0 + 1, y1 = y0 + 1;
        float wb = my_aw * s_vis[k][sq];
        float w00 = (1.f - lx) * (1.f - ly) * wb;
        float w01 = lx * (1.f - ly) * wb;
        float w10 = (1.f - lx) * ly * wb;
        float w11 = lx * ly * wb;
        bool vx0 = (x0 >= 0) & (x0 < Wl), vx1 = (x1 >= 0) & (x1 < Wl);
        bool vy0 = (y0 >= 0) & (y0 < Hl), vy1 = (y1 >= 0) & (y1 < Hl);
        uint4 o;
        o.x = (vx0 & vy0) ? (((unsigned)(base + y0 * Wl + x0) << 16) | f32_to_bf16(w00)) : 0u;
        o.y = (vx1 & vy0) ? (((unsigned)(base + y0 * Wl + x1) << 16) | f32_to_bf16(w01)) : 0u;
        o.z = (vx0 & vy1) ? (((unsigned)(base + y1 * Wl + x0) << 16) | f32_to_bf16(w10)) : 0u;
        o.w = (vx1 & vy1) ? (((unsigned)(base + y1 * Wl + x1) << 16) | f32_to_bf16(w11)) : 0u;
        tab[k] = o;
    }
    __syncthreads();   // orders s_nvis writes for the epilogue readers

    // ---- gather: each lane pair (cg2=0/1) covers tuples {2tp, 2tp+1} ----
    f32x2 A[8] = {};

    #pragma unroll
    for (int k = 0; k < NCAMS; ++k) {
        const unsigned char* vkh =            // wave-uniform slice base
            vb + (size_t)((k * 8 + h) * (LTOT * 32));
        uint4 mine = tab[k];
        uint4 oth;
        oth.x = (unsigned)__shfl_xor((int)mine.x, 1, 64);
        oth.y = (unsigned)__shfl_xor((int)mine.y, 1, 64);
        oth.z = (unsigned)__shfl_xor((int)mine.z, 1, 64);
        oth.w = (unsigned)__shfl_xor((int)mine.w, 1, 64);
        #pragma unroll
        for (int t = 0; t < 2; ++t) {
            uint4 t4 = (t == 0) ? mine : oth;   // order immaterial (sum)
            #pragma unroll
            for (int corner = 0; corner < 4; ++corner) {
                unsigned tc = (corner == 0) ? t4.x : (corner == 1) ? t4.y
                            : (corner == 2) ? t4.z : t4.w;
                float w = __uint_as_float(tc << 16);
                f32x2 w2 = {w, w};
                int off = (int)((tc >> 16) << 5) + cg16;   // 32-bit lane offset
                uint4 d = *(const uint4*)(vkh + off);
                A[0] += w2 * __builtin_amdgcn_cvt_pk_f32_fp8(d.x, false);
                A[1] += w2 * __builtin_amdgcn_cvt_pk_f32_fp8(d.x, true);
                A[2] += w2 * __builtin_amdgcn_cvt_pk_f32_fp8(d.y, false);
                A[3] += w2 * __builtin_amdgcn_cvt_pk_f32_fp8(d.y, true);
                A[4] += w2 * __builtin_amdgcn_cvt_pk_f32_fp8(d.z, false);
                A[5] += w2 * __builtin_amdgcn_cvt_pk_f32_fp8(d.z, true);
                A[6] += w2 * __builtin_amdgcn_cvt_pk_f32_fp8(d.w, false);
                A[7] += w2 * __builtin_amdgcn_cvt_pk_f32_fp8(d.w, true);
            }
        }
    }

    // reduce across the 8 tap-threads (lane bits 1..3)
    #pragma unroll
    for (int i = 0; i < 8; ++i) {
        float x0 = A[i].x, x1 = A[i].y;
        x0 += __shfl_xor(x0, 2, 64); x1 += __shfl_xor(x1, 2, 64);
        x0 += __shfl_xor(x0, 4, 64); x1 += __shfl_xor(x1, 4, 64);
        x0 += __shfl_xor(x0, 8, 64); x1 += __shfl_xor(x1, 8, 64);
        A[i].x = x0; A[i].y = x1;
    }

    if ((tid & 14) == 0) {          // tp == 0: two writers per query (cg2 = 0,1)
        int nv = s_nvis[sq];
        float sc = 1.f / (float)(nv > 0 ? nv : 1);
        uint4 o0, o1;
        o0.x = f32_to_bf16(A[0].x * sc) | ((unsigned)f32_to_bf16(A[0].y * sc) << 16);
        o0.y = f32_to_bf16(A[1].x * sc) | ((unsigned)f32_to_bf16(A[1].y * sc) << 16);
        o0.z = f32_to_bf16(A[2].x * sc) | ((unsigned)f32_to_bf16(A[2].y * sc) << 16);
        o0.w = f32_to_bf16(A[3].x * sc) | ((unsigned)f32_to_bf16(A[3].y * sc) << 16);
        o1.x = f32_to_bf16(A[4].x * sc) | ((unsigned)f32_to_bf16(A[4].y * sc) << 16);
        o1.y = f32_to_bf16(A[5].x * sc) | ((unsigned)f32_to_bf16(A[5].y * sc) << 16);
        o1.z = f32_to_bf16(A[6].x * sc) | ((unsigned)f32_to_bf16(A[6].y * sc) << 16);
        o1.w = f32_to_bf16(A[7].x * sc) | ((unsigned)f32_to_bf16(A[7].y * sc) << 16);
        *(uint4*)(outsum + (size_t)n_s * 256 + h * 32 + cg2 * 16)     = o0;
        *(uint4*)(outsum + (size_t)n_s * 256 + h * 32 + cg2 * 16 + 8) = o1;
    }
    if (h == 0 && tid < 16) visb[q0 + tid] = (s_nvis[tid] > 0) ? 1.f : 0.f;
}

// ---------------------------------------------------------------------------
// Fused output-projection + residual + LN1 (phase-1 only of the old fused
// kernel; FFN1 moved to a wide gemm64 launch for occupancy).
// BM=32 BN=256 K=256: x = LN(outsum@WoT + residual algebra), written to
// xout (fp32, for LN2) and xb16 (bf16, A-operand of FFN1).
// ---------------------------------------------------------------------------
__global__ __launch_bounds__(256) void projln1_kernel(
    const unsigned short* __restrict__ A, const unsigned short* __restrict__ BT,
    const float* __restrict__ query, const float* __restrict__ visb,
    const float* __restrict__ b_out, const float* __restrict__ g,
    const float* __restrict__ b,
    float* __restrict__ xout, unsigned short* __restrict__ xb16)
{
    const int K = 256;
    __shared__ __align__(16) unsigned short As[32][40];
    __shared__ __align__(16) unsigned short Bs[256][40];
    __shared__ float sred[2][4][4][2];
    __shared__ float ssred[2][4][4][2];
    __shared__ float s_mu[32], s_rs[32];

    const int tid  = threadIdx.x;
    const int wave = tid >> 6, lane = tid & 63;
    const int wm = wave >> 1, wn = wave & 1;
    const int quad = lane >> 4, l16 = lane & 15;
    const int m0 = blockIdx.x * 32;

    f32x4 acc[8] = {};

    for (int k0 = 0; k0 < K; k0 += 32) {
        {
            int r = tid >> 3, kc = (tid & 7) * 4;
            *(uint2*)&As[r][kc] = *(const uint2*)(A + (size_t)(m0 + r) * K + k0 + kc);
        }
        {
            const unsigned short* src = BT + (size_t)tid * K + k0;
            *(uint4*)&Bs[tid][0]  = *(const uint4*)(src);
            *(uint4*)&Bs[tid][8]  = *(const uint4*)(src + 8);
            *(uint4*)&Bs[tid][16] = *(const uint4*)(src + 16);
            *(uint4*)&Bs[tid][24] = *(const uint4*)(src + 24);
        }
        __syncthreads();
        bf16x8 af = *(const bf16x8*)&As[wm * 16 + l16][quad * 8];
        #pragma unroll
        for (int ni = 0; ni < 8; ++ni) {
            bf16x8 bfr = *(const bf16x8*)&Bs[wn * 128 + ni * 16 + l16][quad * 8];
            acc[ni] = __builtin_amdgcn_mfma_f32_16x16x32_bf16(af, bfr, acc[ni], 0, 0, 0);
        }
        __syncthreads();
    }

    float vals[8][4];
    #pragma unroll
    for (int r = 0; r < 4; ++r) {
        int gm = m0 + wm * 16 + quad * 4 + r;
        float vs = visb[gm];
        float s = 0.f, ss = 0.f;
        #pragma unroll
        for (int ni = 0; ni < 8; ++ni) {
            int gn = wn * 128 + ni * 16 + l16;
            float v = acc[ni][r] + vs * b_out[gn]
                    + query[(size_t)gm * 256 + gn] * (1.f + vs);
            vals[ni][r] = v;
            s += v; ss += v * v;
        }
        #pragma unroll
        for (int m = 1; m < 16; m <<= 1) {
            s  += __shfl_xor(s,  m, 64);
            ss += __shfl_xor(ss, m, 64);
        }
        if (l16 == 0) {
            sred[wm][quad][r][wn]  = s;
            ssred[wm][quad][r][wn] = ss;
        }
    }
    __syncthreads();
    if (tid < 32) {
        int lwm = tid >> 4, lq = (tid >> 2) & 3, lr = tid & 3;
        float s  = sred[lwm][lq][lr][0]  + sred[lwm][lq][lr][1];
        float ss = ssred[lwm][lq][lr][0] + ssred[lwm][lq][lr][1];
        float mu = s * (1.f / 256.f);
        float var = ss * (1.f / 256.f) - mu * mu;
        s_mu[tid] = mu;
        s_rs[tid] = rsqrtf(var + 1e-5f);
    }
    __syncthreads();

    #pragma unroll
    for (int r = 0; r < 4; ++r) {
        int rowl = wm * 16 + quad * 4 + r;
        int gm = m0 + rowl;
        float mu = s_mu[rowl], rs = s_rs[rowl];
        #pragma unroll
        for (int ni = 0; ni < 8; ++ni) {
            int gn = wn * 128 + ni * 16 + l16;
            float res = (vals[ni][r] - mu) * rs * g[gn] + b[gn];
            xout[(size_t)gm * 256 + gn] = res;
            xb16[(size_t)gm * 256 + gn] = f32_to_bf16(res);
        }
    }
}

// ---------------------------------------------------------------------------
// MFMA bf16 GEMM, BM=64 BN=128 BK=32, bf16 A + BT. Split-K over gridDim.z.
// mode 1: relu -> bf16 out; mode 2: plain bf16 out (split-K partials).
// ---------------------------------------------------------------------------
__global__ __launch_bounds__(256) void gemm64_kernel(
    const unsigned short* __restrict__ A, const unsigned short* __restrict__ BT,
    const float* __restrict__ bias, unsigned short* __restrict__ Cb,
    int M, int N, int K, int mode)
{
    __shared__ __align__(16) unsigned short As[64][40];
    __shared__ __align__(16) unsigned short Bs[128][40];

    const int tid  = threadIdx.x;
    const int wave = tid >> 6, lane = tid & 63;
    const int wm = wave >> 1, wn = wave & 1;
    const int quad = lane >> 4, l16 = lane & 15;
    const int m0 = blockIdx.y * 64, n0 = blockIdx.x * 128;
    const int nz = gridDim.z;
    const int klen = K / nz;
    const int kbase = blockIdx.z * klen;

    f32x4 acc[2][4] = {};

    for (int k0 = kbase; k0 < kbase + klen; k0 += 32) {
        {
            int r = tid >> 2, kc = (tid & 3) * 8;
            int gr = m0 + r;
            uint4 d = (gr < M) ? *(const uint4*)(A + (size_t)gr * K + k0 + kc)
                               : make_uint4(0u, 0u, 0u, 0u);
            *(uint4*)&As[r][kc] = d;
        }
        #pragma unroll
        for (int i = 0; i < 2; ++i) {
            int idx = tid + 256 * i;
            int r = idx >> 2, kc = (idx & 3) * 8;
            *(uint4*)&Bs[r][kc] = *(const uint4*)(BT + (size_t)(n0 + r) * K + k0 + kc);
        }
        __syncthreads();
        bf16x8 af[2], bfr[4];
        #pragma unroll
        for (int mi = 0; mi < 2; ++mi)
            af[mi] = *(const bf16x8*)&As[wm * 32 + mi * 16 + l16][quad * 8];
        #pragma unroll
        for (int ni = 0; ni < 4; ++ni)
            bfr[ni] = *(const bf16x8*)&Bs[wn * 64 + ni * 16 + l16][quad * 8];
        #pragma unroll
        for (int mi = 0; mi < 2; ++mi)
            #pragma unroll
            for (int ni = 0; ni < 4; ++ni)
                acc[mi][ni] = __builtin_amdgcn_mfma_f32_16x16x32_bf16(
                    af[mi], bfr[ni], acc[mi][ni], 0, 0, 0);
        __syncthreads();
    }

    const float* bz = (blockIdx.z == 0) ? bias : nullptr;
    unsigned short* Cz = Cb + (size_t)blockIdx.z * M * N;

    #pragma unroll
    for (int mi = 0; mi < 2; ++mi) {
        #pragma unroll
        for (int r = 0; r < 4; ++r) {
            int gm = m0 + wm * 32 + mi * 16 + quad * 4 + r;
            if (gm >= M) continue;
            #pragma unroll
            for (int ni = 0; ni < 4; ++ni) {
                int gn = n0 + wn * 64 + ni * 16 + l16;
                float v = acc[mi][ni][r] + (bz ? bz[gn] : 0.f);
                if (mode == 1) v = fmaxf(v, 0.f);
                Cz[(size_t)gm * N + gn] = f32_to_bf16(v);
            }
        }
    }
}

// ---------------------------------------------------------------------------
// Vectorized LN2: one wave per row; x fp32 + two bf16 split-K halves.
// ---------------------------------------------------------------------------
__global__ __launch_bounds__(256) void ln2v_kernel(
    const float* __restrict__ x, const unsigned short* __restrict__ f0,
    const unsigned short* __restrict__ f1,
    const float* __restrict__ g, const float* __restrict__ b,
    float* __restrict__ out)
{
    int row  = blockIdx.x * 4 + (threadIdx.x >> 6);
    int lane = threadIdx.x & 63;
    size_t base = (size_t)row * 256 + lane * 4;
    float4 xv = *(const float4*)(x + base);
    uint2 u0 = *(const uint2*)(f0 + base);
    uint2 u1 = *(const uint2*)(f1 + base);
    float t0 = xv.x + __uint_as_float(u0.x << 16)        + __uint_as_float(u1.x << 16);
    float t1 = xv.y + __uint_as_float(u0.x & 0xFFFF0000u) + __uint_as_float(u1.x & 0xFFFF0000u);
    float t2 = xv.z + __uint_as_float(u0.y << 16)        + __uint_as_float(u1.y << 16);
    float t3 = xv.w + __uint_as_float(u0.y & 0xFFFF0000u) + __uint_as_float(u1.y & 0xFFFF0000u);
    float s  = t0 + t1 + t2 + t3;
    float ss = t0 * t0 + t1 * t1 + t2 * t2 + t3 * t3;
    #pragma unroll
    for (int m = 1; m < 64; m <<= 1) {
        s  += __shfl_xor(s,  m, 64);
        ss += __shfl_xor(ss, m, 64);
    }
    float mu = s * (1.f / 256.f);
    float rs = rsqrtf(ss * (1.f / 256.f) - mu * mu + 1e-5f);
    float4 gv = *(const float4*)(g + lane * 4);
    float4 bv = *(const float4*)(b + lane * 4);
    float4 o;
    o.x = (t0 - mu) * rs * gv.x + bv.x;
    o.y = (t1 - mu) * rs * gv.y + bv.y;
    o.z = (t2 - mu) * rs * gv.z + bv.z;
    o.w = (t3 - mu) * rs * gv.w + bv.w;
    *(float4*)(out + base) = o;
}

// ---------------------------------------------------------------------------
extern "C" void kernel_launch(void* const* d_in, const int* in_sizes, int n_in,
                              void* d_out, int out_size, void* d_ws, size_t ws_size,
                              hipStream_t stream)
{
    const float* query   = (const float*)d_in[0];
    const float* value   = (const float*)d_in[2];
    const float* refpts  = (const float*)d_in[3];
    const int*   bevmask = (const int*)d_in[6];
    const float* W_value = (const float*)d_in[7];
    const float* b_value = (const float*)d_in[8];
    const float* W_off   = (const float*)d_in[9];
    const float* b_off   = (const float*)d_in[10];
    const float* W_attn  = (const float*)d_in[11];
    const float* b_attn  = (const float*)d_in[12];
    const float* W_out   = (const float*)d_in[13];
    const float* b_out   = (const float*)d_in[14];
    const float* ln1_g   = (const float*)d_in[15];
    const float* ln1_b   = (const float*)d_in[16];
    const float* W1      = (const float*)d_in[17];
    const float* b1      = (const float*)d_in[18];
    const float* W2      = (const float*)d_in[19];
    const float* b2      = (const float*)d_in[20];
    const float* ln2_g   = (const float*)d_in[21];
    const float* ln2_b   = (const float*)d_in[22];
    float* out = (float*)d_out;

    // workspace layout (byte offsets, temporal aliasing):
    //  [0)          vb fp8 12,255,744       (head -> sample)
    //  [0)          xbuf fp32 6,553,600     (projln1 -> ln2) [vb dead]
    //  [13,000,000) hbf bf16 13,107,200     (ffn1 -> ffn2)
    //  [27,000,000) qoffb bf16 3,276,800    (head -> sample)
    //  [27,000,000) xb16 bf16 3,276,800     (projln1 -> ffn1) [qoffb dead]
    //  [31,000,000) qawb bf16 1,638,400    (head -> sample)
    //  [33,000,000) outsum bf16 3,276,800   (sample -> projln1)
    //  [36,500,000) visb 25,600             (sample -> projln1)
    //  [36,600,000) wsT bf16 1,507,328      (wt_head/sample-tail -> GEMMs)
    //  [39,000,000) ffnout bf16 2x3,276,800 (ffn2 -> ln2)
    char* ws = (char*)d_ws;
    unsigned char*  vb     = (unsigned char*)(ws + 0);
    float*          xbuf   = (float*)(ws + 0);
    unsigned short* hbf    = (unsigned short*)(ws + 13000000);
    unsigned short* qoffb  = (unsigned short*)(ws + 27000000);
    unsigned short* xb16   = (unsigned short*)(ws + 27000000);
    unsigned short* qawb   = (unsigned short*)(ws + 31000000);
    unsigned short* outsum = (unsigned short*)(ws + 33000000);
    float*          visb   = (float*)(ws + 36500000);
    unsigned short* wsT    = (unsigned short*)(ws + 36600000);
    unsigned short* ffnout = (unsigned short*)(ws + 39000000);

    unsigned short* WvT = wsT;            // [256][256]
    unsigned short* WqT = wsT + 65536;    // [384][256]
    unsigned short* WoT = wsT + 163840;   // [256][256] (K-permuted)
    unsigned short* W1T = wsT + 229376;   // [1024][256]
    unsigned short* W2T = wsT + 491520;   // [256][1024]

    // L0: head-side weights -> transposed bf16 (160 blocks)
    wt_head_kernel<<<dim3(160), 256, 0, stream>>>(
        W_value, W_off, W_attn, wsT);
    // L1: value proj (750 blocks, fp8 out, ch-permuted) + query proj (300 blocks)
    head_kernel<<<dim3(1050), 256, 0, stream>>>(
        value, query, WvT, WqT, b_value, b_off, b_attn, vb, qoffb, qawb);
    // L2: sampling (3200) + tail weight transpose (576, overlapped)
    sample_kernel<<<dim3(3776), 256, 0, stream>>>(
        vb, qoffb, qawb, refpts, bevmask, W_out, W1, W2, outsum, visb, wsT);
    // L3: x = LN(outsum@WoT + residual) -> xbuf fp32 + xb16 bf16
    projln1_kernel<<<dim3(200), 256, 0, stream>>>(
        outsum, WoT, query, visb, b_out, ln1_g, ln1_b, xbuf, xb16);
    // L4: h = relu(xb16 @ W1 + b1), 800 blocks
    gemm64_kernel<<<dim3(8, 100, 1), 256, 0, stream>>>(
        xb16, W1T, b1, hbf, NQ, DFFN, 256, 1);
    // L5: ffnout[z] = bf16(h @ W2 (+b2 on z=0)), split-K x2
    gemm64_kernel<<<dim3(2, 100, 2), 256, 0, stream>>>(
        hbf, W2T, b2, ffnout, NQ, 256, DFFN, 2);
    // L6: out = LN(x + f0 + f1)
    ln2v_kernel<<<dim3(1600), 256, 0, stream>>>(
        xbuf, ffnout, ffnout + (size_t)NQ * 256, ln2_g, ln2_b, out);
}

// Round 5
// 279.544 us; speedup vs baseline: 3.3689x; 1.0766x over previous
//
#include <hip/hip_runtime.h>
#include <math.h>

#define NQ      6400
#define NCAMS   6
#define LTOT    7979
#define DM      256
#define DFFN    1024

typedef __attribute__((ext_vector_type(8))) short bf16x8;
typedef __attribute__((ext_vector_type(4))) float f32x4;
typedef __attribute__((ext_vector_type(2))) float f32x2;

__device__ inline unsigned short f32_to_bf16(float f) {
    unsigned u = __float_as_uint(f);
    unsigned r = u + 0x7FFF + ((u >> 16) & 1);   // round-to-nearest-even
    return (unsigned short)(r >> 16);
}

// pack 2 f32 -> 2 bf16 in one VALU op (RNE, same rounding as f32_to_bf16)
__device__ inline unsigned cvt_pk_bf16(float lo, float hi) {
    unsigned r;
    asm("v_cvt_pk_bf16_f32 %0, %1, %2" : "=v"(r) : "v"(lo), "v"(hi));
    return r;
}

// ---------------------------------------------------------------------------
// wt_head: transpose+convert only the weights the head kernel needs.
// wsT layout (shorts): WvT@0, WqT@65536 ([384][256]). 160 blocks.
// ---------------------------------------------------------------------------
__global__ __launch_bounds__(256) void wt_head_kernel(
    const float* __restrict__ Wv, const float* __restrict__ Woff,
    const float* __restrict__ Wattn, unsigned short* __restrict__ wsT)
{
    int b = blockIdx.x;
    const float* src; int K, N, t0, dstoff;
    if (b < 64)       { src = Wv;    K = 256; N = 256; t0 = 0;   dstoff = 0; }
    else if (b < 128) { src = Woff;  K = 256; N = 256; t0 = 64;  dstoff = 65536; }
    else              { src = Wattn; K = 256; N = 128; t0 = 128; dstoff = 131072; }
    int t = b - t0;
    int ntn = N >> 5;
    int kt = t / ntn, nt = t - kt * ntn;
    __shared__ float tile[32][33];
    int tx = threadIdx.x & 31, ty = threadIdx.x >> 5;
    #pragma unroll
    for (int i = 0; i < 4; ++i)
        tile[ty + i * 8][tx] = src[(size_t)(kt * 32 + ty + i * 8) * N + nt * 32 + tx];
    __syncthreads();
    #pragma unroll
    for (int i = 0; i < 4; ++i) {
        int nn = nt * 32 + ty + i * 8;
        wsT[dstoff + (size_t)nn * K + kt * 32 + tx] = f32_to_bf16(tile[tx][ty + i * 8]);
    }
}

// ---------------------------------------------------------------------------
// head_kernel: merged value projection + query projections.
//  b <  750 : value proj (BM=BN=128) -> vb FP8 e4m3 head-major
//             (cam, head, pixel, 32ch PERMUTED c' = 2*(c&15)+(c>>4)), 32 B rows.
//             Channel interleave lets each lane pack 2 fp8 per ushort store.
//  else     : query projections (BM=64): bx=0,1 -> qoff (bf16);
//             bx=2 -> softmax -> qaw (bf16)
// A-staging fp32->bf16 uses v_cvt_pk_bf16_f32 (1 VALU / 2 elems) instead of
// the scalar bit-twiddle (~9 VALU / 2 elems) -- staging was the VALU hotspot.
// ---------------------------------------------------------------------------
__global__ __launch_bounds__(256) void head_kernel(
    const float* __restrict__ value, const float* __restrict__ query,
    const unsigned short* __restrict__ WvT, const unsigned short* __restrict__ WqT,
    const float* __restrict__ bv, const float* __restrict__ boff,
    const float* __restrict__ battn,
    unsigned char* __restrict__ vb, unsigned short* __restrict__ qoffb,
    unsigned short* __restrict__ qawb)
{
    __shared__ __align__(16) unsigned char smem[20480];
    const int b = blockIdx.x;
    const int tid = threadIdx.x;
    const int wave = tid >> 6, lane = tid & 63;
    const int wm = wave >> 1, wn = wave & 1;
    const int quad = lane >> 4, l16 = lane & 15;

    if (b < 750) {
        unsigned short (*As)[40] = (unsigned short(*)[40])smem;
        unsigned short (*Bs)[40] = (unsigned short(*)[40])(smem + 10240);
        const int m0 = (b >> 1) * 128, n0 = (b & 1) * 128;
        const int M = NCAMS * LTOT;

        f32x4 acc[4][4] = {};

        for (int k0 = 0; k0 < 256; k0 += 32) {
            #pragma unroll
            for (int i = 0; i < 2; ++i) {          // A: 128x32 fp32 -> bf16
                int idx = tid + 256 * i;
                int r = idx >> 2, kc = (idx & 3) * 8;
                int gr = m0 + r;
                float4 f0, f1;
                if (gr < M) {
                    f0 = *(const float4*)(value + (size_t)gr * 256 + k0 + kc);
                    f1 = *(const float4*)(value + (size_t)gr * 256 + k0 + kc + 4);
                } else { f0 = make_float4(0.f,0.f,0.f,0.f); f1 = f0; }
                uint4 o;
                o.x = cvt_pk_bf16(f0.x, f0.y);
                o.y = cvt_pk_bf16(f0.z, f0.w);
                o.z = cvt_pk_bf16(f1.x, f1.y);
                o.w = cvt_pk_bf16(f1.z, f1.w);
                *(uint4*)&As[r][kc] = o;
            }
            #pragma unroll
            for (int i = 0; i < 2; ++i) {          // B: WvT bf16, uint4
                int idx = tid + 256 * i;
                int r = idx >> 2, kc = (idx & 3) * 8;
                *(uint4*)&Bs[r][kc] = *(const uint4*)(WvT + (size_t)(n0 + r) * 256 + k0 + kc);
            }
            __syncthreads();
            bf16x8 af[4], bfr[4];
            #pragma unroll
            for (int mi = 0; mi < 4; ++mi)
                af[mi] = *(const bf16x8*)&As[wm * 64 + mi * 16 + l16][quad * 8];
            #pragma unroll
            for (int ni = 0; ni < 4; ++ni)
                bfr[ni] = *(const bf16x8*)&Bs[wn * 64 + ni * 16 + l16][quad * 8];
            #pragma unroll
            for (int mi = 0; mi < 4; ++mi)
                #pragma unroll
                for (int ni = 0; ni < 4; ++ni)
                    acc[mi][ni] = __builtin_amdgcn_mfma_f32_16x16x32_bf16(
                        af[mi], bfr[ni], acc[mi][ni], 0, 0, 0);
            __syncthreads();
        }

        // epilogue: pack channel pairs (c, c+16) -> adjacent bytes (2c', 2c'+1)
        #pragma unroll
        for (int mi = 0; mi < 4; ++mi) {
            #pragma unroll
            for (int r = 0; r < 4; ++r) {
                int gm = m0 + wm * 64 + mi * 16 + quad * 4 + r;
                if (gm >= M) continue;
                int cam = gm / LTOT;
                int pix = gm - cam * LTOT;
                #pragma unroll
                for (int p = 0; p < 2; ++p) {
                    int gn0 = n0 + wn * 64 + p * 32 + l16;   // c = l16 (mod 32)
                    int head = gn0 >> 5;
                    float v0 = acc[mi][2 * p][r]     + bv[gn0];
                    float v1 = acc[mi][2 * p + 1][r] + bv[gn0 + 16];
                    int pk = __builtin_amdgcn_cvt_pk_fp8_f32(v0, v1, 0, false);
                    *(unsigned short*)(vb + (((size_t)(cam * 8 + head)) * LTOT + pix) * 32
                                       + 2 * l16) = (unsigned short)pk;
                }
            }
        }
    } else {
        unsigned short (*As)[40] = (unsigned short(*)[40])smem;
        unsigned short (*Bs)[40] = (unsigned short(*)[40])(smem + 5120);
        const int t = b - 750;
        const int bx = t / 100, by = t % 100;
        const int m0 = by * 64, n0 = bx * 128;
        const int is_attn = (bx == 2);

        f32x4 acc[2][4] = {};

        for (int k0 = 0; k0 < 256; k0 += 32) {
            {                                       // A: 64x32 fp32 -> bf16
                int r = tid >> 2, kc = (tid & 3) * 8;
                float4 f0 = *(const float4*)(query + (size_t)(m0 + r) * 256 + k0 + kc);
                float4 f1 = *(const float4*)(query + (size_t)(m0 + r) * 256 + k0 + kc + 4);
                uint4 o;
                o.x = cvt_pk_bf16(f0.x, f0.y);
                o.y = cvt_pk_bf16(f0.z, f0.w);
                o.z = cvt_pk_bf16(f1.x, f1.y);
                o.w = cvt_pk_bf16(f1.z, f1.w);
                *(uint4*)&As[r][kc] = o;
            }
            #pragma unroll
            for (int i = 0; i < 2; ++i) {           // B: WqT bf16, uint4
                int idx = tid + 256 * i;
                int r = idx >> 2, kc = (idx & 3) * 8;
                *(uint4*)&Bs[r][kc] = *(const uint4*)(WqT + (size_t)(n0 + r) * 256 + k0 + kc);
            }
            __syncthreads();
            bf16x8 af[2], bfr[4];
            #pragma unroll
            for (int mi = 0; mi < 2; ++mi)
                af[mi] = *(const bf16x8*)&As[wm * 32 + mi * 16 + l16][quad * 8];
            #pragma unroll
            for (int ni = 0; ni < 4; ++ni)
                bfr[ni] = *(const bf16x8*)&Bs[wn * 64 + ni * 16 + l16][quad * 8];
            #pragma unroll
            for (int mi = 0; mi < 2; ++mi)
                #pragma unroll
                for (int ni = 0; ni < 4; ++ni)
                    acc[mi][ni] = __builtin_amdgcn_mfma_f32_16x16x32_bf16(
                        af[mi], bfr[ni], acc[mi][ni], 0, 0, 0);
            __syncthreads();
        }

        if (is_attn) {
            #pragma unroll
            for (int mi = 0; mi < 2; ++mi) {
                #pragma unroll
                for (int r = 0; r < 4; ++r) {
                    int gm = m0 + wm * 32 + mi * 16 + quad * 4 + r;
                    #pragma unroll
                    for (int ni = 0; ni < 4; ++ni) {
                        int gn = wn * 64 + ni * 16 + l16;
                        float v = acc[mi][ni][r] + battn[gn];
                        float mx = v;
                        #pragma unroll
                        for (int s = 1; s < 16; s <<= 1)
                            mx = fmaxf(mx, __shfl_xor(mx, s, 64));
                        float e = __expf(v - mx);
                        float sum = e;
                        #pragma unroll
                        for (int s = 1; s < 16; s <<= 1)
                            sum += __shfl_xor(sum, s, 64);
                        qawb[(size_t)gm * 128 + gn] = f32_to_bf16(e / sum);
                    }
                }
            }
        } else {
            #pragma unroll
            for (int mi = 0; mi < 2; ++mi) {
                #pragma unroll
                for (int r = 0; r < 4; ++r) {
                    int gm = m0 + wm * 32 + mi * 16 + quad * 4 + r;
                    #pragma unroll
                    for (int ni = 0; ni < 4; ++ni) {
                        int gn = n0 + wn * 64 + ni * 16 + l16;
                        qoffb[(size_t)gm * 256 + gn] = f32_to_bf16(acc[mi][ni][r] + boff[gn]);
                    }
                }
            }
        }
    }
}

// ---------------------------------------------------------------------------
// sample_kernel: b < 3200 -> head-partitioned fp8 deformable sampling with
// packed f32x2 accumulation; b >= 3200 -> tail weight transpose
// (Wout/W1/W2 -> WoT/W1T/W2T), overlapped with the sampling tail.
// Accumulate mapping: 16 threads/query = 8 tap-threads (2 tuples each)
// x 2 ch-groups (16 fp8 ch each, dwordx4 gathers).
// EXACT revert to the verified 47.8 us version (R2-R4 lesson: the LDS table
// + this schedule is the stable optimum; LDS was never the occupancy binder).
// vb channels are interleave-permuted; outsum is written in permuted order
// and WoT's K index is permuted to match (see tail transpose).
// ---------------------------------------------------------------------------
__global__ __launch_bounds__(256) void sample_kernel(
    const unsigned char* __restrict__ vb,  // (6, 8, 7979, 32) fp8 e4m3, ch-permuted
    const unsigned short* __restrict__ qoffb, // (6400, 256) bf16
    const unsigned short* __restrict__ qawb,  // (6400, 128) bf16
    const float* __restrict__ refpts,      // (6, 1, 6400, 4, 2)
    const int*   __restrict__ bev_mask,    // (6, 1, 6400, 4)
    const float* __restrict__ Wout, const float* __restrict__ W1,
    const float* __restrict__ W2,
    unsigned short* __restrict__ outsum,   // (6400, 256) bf16 (ch-permuted)
    float* __restrict__ visb,              // (6400)
    unsigned short* __restrict__ wsT)
{
    __shared__ __align__(16) unsigned s_tab[NCAMS][272][4];   // [cam][sq*17+tup][corner]
    __shared__ float s_vis[NCAMS][16];
    __shared__ int   s_nvis[16];

    const int bid = blockIdx.x;
    const int tid = threadIdx.x;

    if (bid >= 3200) {
        // ---- tail weight transpose (reuses s_tab as the LDS tile) ----
        int t = bid - 3200;
        const float* src; int K, N, dstoff;
        if (t < 64)       { src = Wout; K = 256;  N = 256;  dstoff = 163840; }
        else if (t < 320) { src = W1;   K = 256;  N = 1024; dstoff = 229376; t -= 64; }
        else              { src = W2;   K = 1024; N = 256;  dstoff = 491520; t -= 320; }
        int ntn = N >> 5;
        int kt = t / ntn, nt = t - kt * ntn;
        float (*tile)[33] = (float(*)[33])&s_tab[0][0][0];
        int tx = tid & 31, ty = tid >> 5;
        #pragma unroll
        for (int i = 0; i < 4; ++i)
            tile[ty + i * 8][tx] = src[(size_t)(kt * 32 + ty + i * 8) * N + nt * 32 + tx];
        __syncthreads();
        // WoT only: permute K index within each 32-channel head block to match
        // the vb/outsum channel interleave: c' = 2*(c&15) | (c>>4)
        int txp = (dstoff == 163840) ? (((tx & 15) << 1) | (tx >> 4)) : tx;
        #pragma unroll
        for (int i = 0; i < 4; ++i) {
            int nn = nt * 32 + ty + i * 8;
            wsT[dstoff + (size_t)nn * K + kt * 32 + txp] = f32_to_bf16(tile[tx][ty + i * 8]);
        }
        return;
    }

    const int h   = bid & 7;
    const int q0  = (bid >> 3) * 16;
    const int sq  = tid >> 4;
    const int tup = tid & 15;
    const int lvl = tup >> 2;
    const int n_s = q0 + sq;

    if (tid < 96) {
        int cam = tid >> 4, q = tid & 15;
        const int* bm = bev_mask + ((size_t)cam * NQ + q0 + q) * 4;
        s_vis[cam][q] = ((bm[0] + bm[1] + bm[2] + bm[3]) > 0) ? 1.f : 0.f;
    }
    __syncthreads();
    if (tid >= 32 && tid < 48) {
        int q = tid - 32;
        float s = 0.f;
        #pragma unroll
        for (int cam = 0; cam < NCAMS; ++cam) s += s_vis[cam][q];
        s_nvis[q] = (int)s;
    }

    unsigned uoff = *(const unsigned*)(qoffb + (size_t)n_s * 256 + h * 32 + tup * 2);
    const float offx  = __uint_as_float(uoff << 16);
    const float offy  = __uint_as_float(uoff & 0xFFFF0000u);
    const float my_aw = __uint_as_float((unsigned)qawb[(size_t)n_s * 128 + h * 16 + tup] << 16);
    const int Wl   = (lvl == 0) ? 100 : (lvl == 1) ? 50 : (lvl == 2) ? 25 : 13;
    const int Hl   = (lvl == 0) ? 60  : (lvl == 1) ? 30 : (lvl == 2) ? 15 : 8;
    const int base = (lvl == 0) ? 0   : (lvl == 1) ? 6000 : (lvl == 2) ? 7500 : 7875;
    const float dx = offx / (float)Wl;
    const float dy = offy / (float)Hl;
    const int tabi = sq * 17 + tup;

    float2 rp[NCAMS];
    #pragma unroll
    for (int k = 0; k < NCAMS; ++k)
        rp[k] = *(const float2*)(refpts + (((size_t)k * NQ + n_s) * 4 + lvl) * 2);
    __syncthreads();   // covers s_nvis writes

    #pragma unroll
    for (int k = 0; k < NCAMS; ++k) {
        float fx = (rp[k].x + dx) * (float)Wl - 0.5f;
        float fy = (rp[k].y + dy) * (float)Hl - 0.5f;
        float x0f = floorf(fx), y0f = floorf(fy);
        float lx = fx - x0f, ly = fy - y0f;
        int x0 = (int)x0f, y0 = (int)y0f;
        int x1 = x0 + 1, y1 = y0 + 1;
        float wb = my_aw * s_vis[k][sq];
        float w00 = (1.f - lx) * (1.f - ly) * wb;
        float w01 = lx * (1.f - ly) * wb;
        float w10 = (1.f - lx) * ly * wb;
        float w11 = lx * ly * wb;
        bool vx0 = (x0 >= 0) & (x0 < Wl), vx1 = (x1 >= 0) & (x1 < Wl);
        bool vy0 = (y0 >= 0) & (y0 < Hl), vy1 = (y1 >= 0) & (y1 < Hl);
        uint4 o;
        o.x = (vx0 & vy0) ? (((unsigned)(base + y0 * Wl + x0) << 16) | f32_to_bf16(w00)) : 0u;
        o.y = (vx1 & vy0) ? (((unsigned)(base + y0 * Wl + x1) << 16) | f32_to_bf16(w01)) : 0u;
        o.z = (vx0 & vy1) ? (((unsigned)(base + y1 * Wl + x0) << 16) | f32_to_bf16(w10)) : 0u;
        o.w = (vx1 & vy1) ? (((unsigned)(base + y1 * Wl + x1) << 16) | f32_to_bf16(w11)) : 0u;
        *(uint4*)&s_tab[k][tabi][0] = o;
    }
    __syncthreads();

    // ---- accumulate: tp = 8 tap-threads (2 tuples), cg2 = 2 ch-groups of 16 ----
    const int tp  = (tid >> 1) & 7;
    const int cg2 = tid & 1;

    f32x2 A[8] = {};

    #pragma unroll
    for (int k = 0; k < NCAMS; ++k) {
        const char* vkh = (const char*)vb + (size_t)(k * 8 + h) * (LTOT * 32) + cg2 * 16;
        #pragma unroll
        for (int t = 0; t < 2; ++t) {
            uint4 t4 = *(const uint4*)&s_tab[k][sq * 17 + tp * 2 + t][0];
            #pragma unroll
            for (int corner = 0; corner < 4; ++corner) {
                unsigned tc = (corner == 0) ? t4.x : (corner == 1) ? t4.y
                            : (corner == 2) ? t4.z : t4.w;
                float w = __uint_as_float(tc << 16);
                f32x2 w2 = {w, w};
                uint4 d = *(const uint4*)(vkh + ((size_t)(tc >> 16) << 5));
                A[0] += w2 * __builtin_amdgcn_cvt_pk_f32_fp8(d.x, false);
                A[1] += w2 * __builtin_amdgcn_cvt_pk_f32_fp8(d.x, true);
                A[2] += w2 * __builtin_amdgcn_cvt_pk_f32_fp8(d.y, false);
                A[3] += w2 * __builtin_amdgcn_cvt_pk_f32_fp8(d.y, true);
                A[4] += w2 * __builtin_amdgcn_cvt_pk_f32_fp8(d.z, false);
                A[5] += w2 * __builtin_amdgcn_cvt_pk_f32_fp8(d.z, true);
                A[6] += w2 * __builtin_amdgcn_cvt_pk_f32_fp8(d.w, false);
                A[7] += w2 * __builtin_amdgcn_cvt_pk_f32_fp8(d.w, true);
            }
        }
    }

    // reduce across the 8 tap-threads (lane bits 1..3)
    #pragma unroll
    for (int i = 0; i < 8; ++i) {
        float x0 = A[i].x, x1 = A[i].y;
        x0 += __shfl_xor(x0, 2, 64); x1 += __shfl_xor(x1, 2, 64);
        x0 += __shfl_xor(x0, 4, 64); x1 += __shfl_xor(x1, 4, 64);
        x0 += __shfl_xor(x0, 8, 64); x1 += __shfl_xor(x1, 8, 64);
        A[i].x = x0; A[i].y = x1;
    }

    if ((tid & 14) == 0) {          // tp == 0: two writers per query (cg2 = 0,1)
        int nv = s_nvis[sq];
        float sc = 1.f / (float)(nv > 0 ? nv : 1);
        uint4 o0, o1;
        o0.x = f32_to_bf16(A[0].x * sc) | ((unsigned)f32_to_bf16(A[0].y * sc) << 16);
        o0.y = f32_to_bf16(A[1].x * sc) | ((unsigned)f32_to_bf16(A[1].y * sc) << 16);
        o0.z = f32_to_bf16(A[2].x * sc) | ((unsigned)f32_to_bf16(A[2].y * sc) << 16);
        o0.w = f32_to_bf16(A[3].x * sc) | ((unsigned)f32_to_bf16(A[3].y * sc) << 16);
        o1.x = f32_to_bf16(A[4].x * sc) | ((unsigned)f32_to_bf16(A[4].y * sc) << 16);
        o1.y = f32_to_bf16(A[5].x * sc) | ((unsigned)f32_to_bf16(A[5].y * sc) << 16);
        o1.z = f32_to_bf16(A[6].x * sc) | ((unsigned)f32_to_bf16(A[6].y * sc) << 16);
        o1.w = f32_to_bf16(A[7].x * sc) | ((unsigned)f32_to_bf16(A[7].y * sc) << 16);
        *(uint4*)(outsum + (size_t)n_s * 256 + h * 32 + cg2 * 16)     = o0;
        *(uint4*)(outsum + (size_t)n_s * 256 + h * 32 + cg2 * 16 + 8) = o1;
    }
    if (h == 0 && tid < 16) visb[q0 + tid] = (s_nvis[tid] > 0) ? 1.f : 0.f;
}

// ---------------------------------------------------------------------------
// Fused output-projection + residual + LN1 (phase-1 only of the old fused
// kernel; FFN1 moved to a wide gemm64 launch for occupancy).
// BM=32 BN=256 K=256: x = LN(outsum@WoT + residual algebra), written to
// xout (fp32, for LN2) and xb16 (bf16, A-operand of FFN1).
// ---------------------------------------------------------------------------
__global__ __launch_bounds__(256) void projln1_kernel(
    const unsigned short* __restrict__ A, const unsigned short* __restrict__ BT,
    const float* __restrict__ query, const float* __restrict__ visb,
    const float* __restrict__ b_out, const float* __restrict__ g,
    const float* __restrict__ b,
    float* __restrict__ xout, unsigned short* __restrict__ xb16)
{
    const int K = 256;
    __shared__ __align__(16) unsigned short As[32][40];
    __shared__ __align__(16) unsigned short Bs[256][40];
    __shared__ float sred[2][4][4][2];
    __shared__ float ssred[2][4][4][2];
    __shared__ float s_mu[32], s_rs[32];

    const int tid  = threadIdx.x;
    const int wave = tid >> 6, lane = tid & 63;
    const int wm = wave >> 1, wn = wave & 1;
    const int quad = lane >> 4, l16 = lane & 15;
    const int m0 = blockIdx.x * 32;

    f32x4 acc[8] = {};

    for (int k0 = 0; k0 < K; k0 += 32) {
        {
            int r = tid >> 3, kc = (tid & 7) * 4;
            *(uint2*)&As[r][kc] = *(const uint2*)(A + (size_t)(m0 + r) * K + k0 + kc);
        }
        {
            const unsigned short* src = BT + (size_t)tid * K + k0;
            *(uint4*)&Bs[tid][0]  = *(const uint4*)(src);
            *(uint4*)&Bs[tid][8]  = *(const uint4*)(src + 8);
            *(uint4*)&Bs[tid][16] = *(const uint4*)(src + 16);
            *(uint4*)&Bs[tid][24] = *(const uint4*)(src + 24);
        }
        __syncthreads();
        bf16x8 af = *(const bf16x8*)&As[wm * 16 + l16][quad * 8];
        #pragma unroll
        for (int ni = 0; ni < 8; ++ni) {
            bf16x8 bfr = *(const bf16x8*)&Bs[wn * 128 + ni * 16 + l16][quad * 8];
            acc[ni] = __builtin_amdgcn_mfma_f32_16x16x32_bf16(af, bfr, acc[ni], 0, 0, 0);
        }
        __syncthreads();
    }

    float vals[8][4];
    #pragma unroll
    for (int r = 0; r < 4; ++r) {
        int gm = m0 + wm * 16 + quad * 4 + r;
        float vs = visb[gm];
        float s = 0.f, ss = 0.f;
        #pragma unroll
        for (int ni = 0; ni < 8; ++ni) {
            int gn = wn * 128 + ni * 16 + l16;
            float v = acc[ni][r] + vs * b_out[gn]
                    + query[(size_t)gm * 256 + gn] * (1.f + vs);
            vals[ni][r] = v;
            s += v; ss += v * v;
        }
        #pragma unroll
        for (int m = 1; m < 16; m <<= 1) {
            s  += __shfl_xor(s,  m, 64);
            ss += __shfl_xor(ss, m, 64);
        }
        if (l16 == 0) {
            sred[wm][quad][r][wn]  = s;
            ssred[wm][quad][r][wn] = ss;
        }
    }
    __syncthreads();
    if (tid < 32) {
        int lwm = tid >> 4, lq = (tid >> 2) & 3, lr = tid & 3;
        float s  = sred[lwm][lq][lr][0]  + sred[lwm][lq][lr][1];
        float ss = ssred[lwm][lq][lr][0] + ssred[lwm][lq][lr][1];
        float mu = s * (1.f / 256.f);
        float var = ss * (1.f / 256.f) - mu * mu;
        s_mu[tid] = mu;
        s_rs[tid] = rsqrtf(var + 1e-5f);
    }
    __syncthreads();

    #pragma unroll
    for (int r = 0; r < 4; ++r) {
        int rowl = wm * 16 + quad * 4 + r;
        int gm = m0 + rowl;
        float mu = s_mu[rowl], rs = s_rs[rowl];
        #pragma unroll
        for (int ni = 0; ni < 8; ++ni) {
            int gn = wn * 128 + ni * 16 + l16;
            float res = (vals[ni][r] - mu) * rs * g[gn] + b[gn];
            xout[(size_t)gm * 256 + gn] = res;
            xb16[(size_t)gm * 256 + gn] = f32_to_bf16(res);
        }
    }
}

// ---------------------------------------------------------------------------
// MFMA bf16 GEMM, BM=64 BN=128 BK=32, bf16 A + BT. Split-K over gridDim.z.
// mode 1: relu -> bf16 out; mode 2: plain bf16 out (split-K partials).
// ---------------------------------------------------------------------------
__global__ __launch_bounds__(256) void gemm64_kernel(
    const unsigned short* __restrict__ A, const unsigned short* __restrict__ BT,
    const float* __restrict__ bias, unsigned short* __restrict__ Cb,
    int M, int N, int K, int mode)
{
    __shared__ __align__(16) unsigned short As[64][40];
    __shared__ __align__(16) unsigned short Bs[128][40];

    const int tid  = threadIdx.x;
    const int wave = tid >> 6, lane = tid & 63;
    const int wm = wave >> 1, wn = wave & 1;
    const int quad = lane >> 4, l16 = lane & 15;
    const int m0 = blockIdx.y * 64, n0 = blockIdx.x * 128;
    const int nz = gridDim.z;
    const int klen = K / nz;
    const int kbase = blockIdx.z * klen;

    f32x4 acc[2][4] = {};

    for (int k0 = kbase; k0 < kbase + klen; k0 += 32) {
        {
            int r = tid >> 2, kc = (tid & 3) * 8;
            int gr = m0 + r;
            uint4 d = (gr < M) ? *(const uint4*)(A + (size_t)gr * K + k0 + kc)
                               : make_uint4(0u, 0u, 0u, 0u);
            *(uint4*)&As[r][kc] = d;
        }
        #pragma unroll
        for (int i = 0; i < 2; ++i) {
            int idx = tid + 256 * i;
            int r = idx >> 2, kc = (idx & 3) * 8;
            *(uint4*)&Bs[r][kc] = *(const uint4*)(BT + (size_t)(n0 + r) * K + k0 + kc);
        }
        __syncthreads();
        bf16x8 af[2], bfr[4];
        #pragma unroll
        for (int mi = 0; mi < 2; ++mi)
            af[mi] = *(const bf16x8*)&As[wm * 32 + mi * 16 + l16][quad * 8];
        #pragma unroll
        for (int ni = 0; ni < 4; ++ni)
            bfr[ni] = *(const bf16x8*)&Bs[wn * 64 + ni * 16 + l16][quad * 8];
        #pragma unroll
        for (int mi = 0; mi < 2; ++mi)
            #pragma unroll
            for (int ni = 0; ni < 4; ++ni)
                acc[mi][ni] = __builtin_amdgcn_mfma_f32_16x16x32_bf16(
                    af[mi], bfr[ni], acc[mi][ni], 0, 0, 0);
        __syncthreads();
    }

    const float* bz = (blockIdx.z == 0) ? bias : nullptr;
    unsigned short* Cz = Cb + (size_t)blockIdx.z * M * N;

    #pragma unroll
    for (int mi = 0; mi < 2; ++mi) {
        #pragma unroll
        for (int r = 0; r < 4; ++r) {
            int gm = m0 + wm * 32 + mi * 16 + quad * 4 + r;
            if (gm >= M) continue;
            #pragma unroll
            for (int ni = 0; ni < 4; ++ni) {
                int gn = n0 + wn * 64 + ni * 16 + l16;
                float v = acc[mi][ni][r] + (bz ? bz[gn] : 0.f);
                if (mode == 1) v = fmaxf(v, 0.f);
                Cz[(size_t)gm * N + gn] = f32_to_bf16(v);
            }
        }
    }
}

// ---------------------------------------------------------------------------
// Vectorized LN2: one wave per row; x fp32 + two bf16 split-K halves.
// ---------------------------------------------------------------------------
__global__ __launch_bounds__(256) void ln2v_kernel(
    const float* __restrict__ x, const unsigned short* __restrict__ f0,
    const unsigned short* __restrict__ f1,
    const float* __restrict__ g, const float* __restrict__ b,
    float* __restrict__ out)
{
    int row  = blockIdx.x * 4 + (threadIdx.x >> 6);
    int lane = threadIdx.x & 63;
    size_t base = (size_t)row * 256 + lane * 4;
    float4 xv = *(const float4*)(x + base);
    uint2 u0 = *(const uint2*)(f0 + base);
    uint2 u1 = *(const uint2*)(f1 + base);
    float t0 = xv.x + __uint_as_float(u0.x << 16)        + __uint_as_float(u1.x << 16);
    float t1 = xv.y + __uint_as_float(u0.x & 0xFFFF0000u) + __uint_as_float(u1.x & 0xFFFF0000u);
    float t2 = xv.z + __uint_as_float(u0.y << 16)        + __uint_as_float(u1.y << 16);
    float t3 = xv.w + __uint_as_float(u0.y & 0xFFFF0000u) + __uint_as_float(u1.y & 0xFFFF0000u);
    float s  = t0 + t1 + t2 + t3;
    float ss = t0 * t0 + t1 * t1 + t2 * t2 + t3 * t3;
    #pragma unroll
    for (int m = 1; m < 64; m <<= 1) {
        s  += __shfl_xor(s,  m, 64);
        ss += __shfl_xor(ss, m, 64);
    }
    float mu = s * (1.f / 256.f);
    float rs = rsqrtf(ss * (1.f / 256.f) - mu * mu + 1e-5f);
    float4 gv = *(const float4*)(g + lane * 4);
    float4 bv = *(const float4*)(b + lane * 4);
    float4 o;
    o.x = (t0 - mu) * rs * gv.x + bv.x;
    o.y = (t1 - mu) * rs * gv.y + bv.y;
    o.z = (t2 - mu) * rs * gv.z + bv.z;
    o.w = (t3 - mu) * rs * gv.w + bv.w;
    *(float4*)(out + base) = o;
}

// ---------------------------------------------------------------------------
extern "C" void kernel_launch(void* const* d_in, const int* in_sizes, int n_in,
                              void* d_out, int out_size, void* d_ws, size_t ws_size,
                              hipStream_t stream)
{
    const float* query   = (const float*)d_in[0];
    const float* value   = (const float*)d_in[2];
    const float* refpts  = (const float*)d_in[3];
    const int*   bevmask = (const int*)d_in[6];
    const float* W_value = (const float*)d_in[7];
    const float* b_value = (const float*)d_in[8];
    const float* W_off   = (const float*)d_in[9];
    const float* b_off   = (const float*)d_in[10];
    const float* W_attn  = (const float*)d_in[11];
    const float* b_attn  = (const float*)d_in[12];
    const float* W_out   = (const float*)d_in[13];
    const float* b_out   = (const float*)d_in[14];
    const float* ln1_g   = (const float*)d_in[15];
    const float* ln1_b   = (const float*)d_in[16];
    const float* W1      = (const float*)d_in[17];
    const float* b1      = (const float*)d_in[18];
    const float* W2      = (const float*)d_in[19];
    const float* b2      = (const float*)d_in[20];
    const float* ln2_g   = (const float*)d_in[21];
    const float* ln2_b   = (const float*)d_in[22];
    float* out = (float*)d_out;

    // workspace layout (byte offsets, temporal aliasing):
    //  [0)          vb fp8 12,255,744       (head -> sample)
    //  [0)          xbuf fp32 6,553,600     (projln1 -> ln2) [vb dead]
    //  [13,000,000) hbf bf16 13,107,200     (ffn1 -> ffn2)
    //  [27,000,000) qoffb bf16 3,276,800    (head -> sample)
    //  [27,000,000) xb16 bf16 3,276,800     (projln1 -> ffn1) [qoffb dead]
    //  [31,000,000) qawb bf16 1,638,400     (head -> sample)
    //  [33,000,000) outsum bf16 3,276,800   (sample -> projln1)
    //  [36,500,000) visb 25,600             (sample -> projln1)
    //  [36,600,000) wsT bf16 1,507,328      (wt_head/sample-tail -> GEMMs)
    //  [39,000,000) ffnout bf16 2x3,276,800 (ffn2 -> ln2)
    char* ws = (char*)d_ws;
    unsigned char*  vb     = (unsigned char*)(ws + 0);
    float*          xbuf   = (float*)(ws + 0);
    unsigned short* hbf    = (unsigned short*)(ws + 13000000);
    unsigned short* qoffb  = (unsigned short*)(ws + 27000000);
    unsigned short* xb16   = (unsigned short*)(ws + 27000000);
    unsigned short* qawb   = (unsigned short*)(ws + 31000000);
    unsigned short* outsum = (unsigned short*)(ws + 33000000);
    float*          visb   = (float*)(ws + 36500000);
    unsigned short* wsT    = (unsigned short*)(ws + 36600000);
    unsigned short* ffnout = (unsigned short*)(ws + 39000000);

    unsigned short* WvT = wsT;            // [256][256]
    unsigned short* WqT = wsT + 65536;    // [384][256]
    unsigned short* WoT = wsT + 163840;   // [256][256] (K-permuted)
    unsigned short* W1T = wsT + 229376;   // [1024][256]
    unsigned short* W2T = wsT + 491520;   // [256][1024]

    // L0: head-side weights -> transposed bf16 (160 blocks)
    wt_head_kernel<<<dim3(160), 256, 0, stream>>>(
        W_value, W_off, W_attn, wsT);
    // L1: value proj (750 blocks, fp8 out, ch-permuted) + query proj (300 blocks)
    head_kernel<<<dim3(1050), 256, 0, stream>>>(
        value, query, WvT, WqT, b_value, b_off, b_attn, vb, qoffb, qawb);
    // L2: sampling (3200) + tail weight transpose (576, overlapped)
    sample_kernel<<<dim3(3776), 256, 0, stream>>>(
        vb, qoffb, qawb, refpts, bevmask, W_out, W1, W2, outsum, visb, wsT);
    // L3: x = LN(outsum@WoT + residual) -> xbuf fp32 + xb16 bf16
    projln1_kernel<<<dim3(200), 256, 0, stream>>>(
        outsum, WoT, query, visb, b_out, ln1_g, ln1_b, xbuf, xb16);
    // L4: h = relu(xb16 @ W1 + b1), 800 blocks
    gemm64_kernel<<<dim3(8, 100, 1), 256, 0, stream>>>(
        xb16, W1T, b1, hbf, NQ, DFFN, 256, 1);
    // L5: ffnout[z] = bf16(h @ W2 (+b2 on z=0)), split-K x2
    gemm64_kernel<<<dim3(2, 100, 2), 256, 0, stream>>>(
        hbf, W2T, b2, ffnout, NQ, 256, DFFN, 2);
    // L6: out = LN(x + f0 + f1)
    ln2v_kernel<<<dim3(1600), 256, 0, stream>>>(
        xbuf, ffnout, ffnout + (size_t)NQ * 256, ln2_g, ln2_b, out);
}